// Round 2
// baseline (609.298 us; speedup 1.0000x reference)
//
#include <hip/hip_runtime.h>
#include <math.h>

using u16 = unsigned short;
using u32 = unsigned int;
using u64 = unsigned long long;
using bf16x8 = __attribute__((ext_vector_type(8))) short;
using f32x4  = __attribute__((ext_vector_type(4))) float;

#define C_DIM   512
#define HEADS   8
#define HDIM    64
#define P_DIM   64
#define A_TOK   256
#define VCAP    256
#define S_TOK   512
#define NWIN    64
#define NROW    32768      // NWIN * S_TOK
#define NPATCH  16384      // NWIN * A_TOK
#define MLP_DIM 2048
#define NV_TOT  2048

__device__ __forceinline__ float bf2f(u16 b) { return __uint_as_float(((u32)b) << 16); }
__device__ __forceinline__ u16 f2bf(float f) {
    u32 u = __float_as_uint(f);
    return (u16)((u + 0x7fffu + ((u >> 16) & 1u)) >> 16);   // RNE
}
__device__ __forceinline__ float4 bf4f(ushort4 v) {
    return make_float4(bf2f(v.x), bf2f(v.y), bf2f(v.z), bf2f(v.w));
}
// dtype-agnostic loads from RAW inputs: isbf=1 -> bf16, else f32
__device__ __forceinline__ float ldf(const void* p, size_t e, int isbf) {
    return isbf ? bf2f(((const u16*)p)[e]) : ((const float*)p)[e];
}
__device__ __forceinline__ float4 ld4(const void* p, size_t e, int isbf) {  // e % 4 == 0
    if (isbf) return bf4f(*(const ushort4*)((const u16*)p + e));
    return *(const float4*)((const float*)p + e);
}

// ---------------- dtype detector: vote on low-16-bits-as-bf16 plausibility ----------------
__global__ void detect_kernel(const u32* __restrict__ patch, int* __restrict__ flag)
{
    __shared__ int sm[256];
    int t = threadIdx.x;
    int cnt = 0;
    for (int i = t; i < 4096; i += 256) {
        u32 w = patch[i];
        float v = __uint_as_float((w & 0xffffu) << 16);
        float a = fabsf(v);
        if (a > 1e-8f && a < 1e4f) cnt++;
    }
    sm[t] = cnt;
    __syncthreads();
    for (int o = 128; o; o >>= 1) { if (t < o) sm[t] += sm[t + o]; __syncthreads(); }
    if (t == 0) *flag = (sm[0] > 2458) ? 1 : 0;    // >60% plausible => bf16 world
}

// ---------------- weight transpose: in [K][N] -> out [N][K] bf16 ----------------
__global__ void wtrans_kernel(const void* __restrict__ in, u16* __restrict__ out,
                              int K, int N, const int* __restrict__ flagp)
{
    __shared__ u16 tile[32][33];
    int isbf = *flagp;
    int n0 = blockIdx.x * 32, k0 = blockIdx.y * 32;
    int tx = threadIdx.x, ty = threadIdx.y;   // block (32, 8)
    #pragma unroll
    for (int i = 0; i < 4; i++)
        tile[ty + i * 8][tx] = f2bf(ldf(in, (size_t)(k0 + ty + i * 8) * N + (n0 + tx), isbf));
    __syncthreads();
    #pragma unroll
    for (int i = 0; i < 4; i++)
        out[(size_t)(n0 + ty + i * 8) * K + (k0 + tx)] = tile[tx][ty + i * 8];
}

// ---------------- per-window voxel selection (stable order, cap 256) ----------------
__global__ void voxsel_kernel(const int* __restrict__ vy, const int* __restrict__ vx,
                              int* __restrict__ sel)
{
    int n = blockIdx.x;                 // 64 windows, 64 threads (1 wave)
    int lane = threadIdx.x;
    int y0 = (n >> 3) << 3, x0 = (n & 7) << 3;
    int count = 0;
    for (int base = 0; base < NV_TOT; base += 64) {
        int v = base + lane;
        int yy = vy[v], xx = vx[v];
        bool m = (yy >= y0) && (yy < y0 + 16) && (xx >= x0) && (xx < x0 + 16);
        u64 mask = __ballot(m);
        int pos = count + __popcll(mask & ((1ull << lane) - 1ull));
        if (m && pos < VCAP) sel[n * VCAP + pos] = v;
        count += __popcll(mask);
    }
    for (int j = lane; j < VCAP; j += 64)
        if (j >= count) sel[n * VCAP + j] = -1;
}

// ---------------- gather tokens + LN1 -> h (bf16), validity flags ----------------
__global__ __launch_bounds__(256) void ln1_kernel(
    const void* __restrict__ patch, const void* __restrict__ vox,
    const void* __restrict__ g, const void* __restrict__ b,
    const int* __restrict__ sel, const int* __restrict__ flagp,
    u16* __restrict__ h, unsigned char* __restrict__ validk)
{
    int isbf = *flagp;
    int r = blockIdx.x * 4 + (threadIdx.x >> 6);    // one wave per row
    int lane = threadIdx.x & 63;
    int n = r >> 9, s = r & 511;
    const void* tok = nullptr;
    size_t base = 0;
    bool valid;
    if (s < A_TOK) {
        int wy = s >> 4, wx = s & 15;
        int iy = ((n >> 3) << 3) + wy, ix = ((n & 7) << 3) + wx;
        valid = (iy < P_DIM) && (ix < P_DIM);
        tok = patch; base = (size_t)(iy * P_DIM + ix) * C_DIM;
    } else {
        int idx = sel[n * VCAP + (s - A_TOK)];
        valid = (idx >= 0);
        tok = vox; base = valid ? (size_t)idx * C_DIM : 0;
    }
    float4 xa = make_float4(0.f, 0.f, 0.f, 0.f), xb = xa;
    if (valid) {
        xa = ld4(tok, base + lane * 4, isbf);
        xb = ld4(tok, base + 256 + lane * 4, isbf);
    }
    float sum = xa.x + xa.y + xa.z + xa.w + xb.x + xb.y + xb.z + xb.w;
    float sq  = xa.x * xa.x + xa.y * xa.y + xa.z * xa.z + xa.w * xa.w
              + xb.x * xb.x + xb.y * xb.y + xb.z * xb.z + xb.w * xb.w;
    #pragma unroll
    for (int off = 32; off; off >>= 1) {
        sum += __shfl_xor(sum, off, 64);
        sq  += __shfl_xor(sq,  off, 64);
    }
    float mean = sum * (1.f / C_DIM);
    float var  = fmaxf(sq * (1.f / C_DIM) - mean * mean, 0.f);
    float rstd = rsqrtf(var + 1e-5f);
    float4 ga = ld4(g, lane * 4, isbf);
    float4 gb = ld4(g, 256 + lane * 4, isbf);
    float4 ba = ld4(b, lane * 4, isbf);
    float4 bb = ld4(b, 256 + lane * 4, isbf);
    ushort4 oa, ob;
    oa.x = f2bf((xa.x - mean) * rstd * ga.x + ba.x);
    oa.y = f2bf((xa.y - mean) * rstd * ga.y + ba.y);
    oa.z = f2bf((xa.z - mean) * rstd * ga.z + ba.z);
    oa.w = f2bf((xa.w - mean) * rstd * ga.w + ba.w);
    ob.x = f2bf((xb.x - mean) * rstd * gb.x + bb.x);
    ob.y = f2bf((xb.y - mean) * rstd * gb.y + bb.y);
    ob.z = f2bf((xb.z - mean) * rstd * gb.z + bb.z);
    ob.w = f2bf((xb.w - mean) * rstd * gb.w + bb.w);
    ((ushort4*)(h + (size_t)r * C_DIM))[lane]      = oa;
    ((ushort4*)(h + (size_t)r * C_DIM))[lane + 64] = ob;
    if (lane == 0) validk[r] = valid ? 1 : 0;
}

// ---------------- LN2 over f32 rows -> bf16 ----------------
__global__ __launch_bounds__(256) void ln2_kernel(
    const float* __restrict__ x,
    const void* __restrict__ g, const void* __restrict__ b,
    const int* __restrict__ flagp,
    u16* __restrict__ h2)
{
    int isbf = *flagp;
    int r = blockIdx.x * 4 + (threadIdx.x >> 6);
    int lane = threadIdx.x & 63;
    const float* src = x + (size_t)r * C_DIM;
    float4 xa = ((const float4*)src)[lane];
    float4 xb = ((const float4*)src)[lane + 64];
    float sum = xa.x + xa.y + xa.z + xa.w + xb.x + xb.y + xb.z + xb.w;
    float sq  = xa.x * xa.x + xa.y * xa.y + xa.z * xa.z + xa.w * xa.w
              + xb.x * xb.x + xb.y * xb.y + xb.z * xb.z + xb.w * xb.w;
    #pragma unroll
    for (int off = 32; off; off >>= 1) {
        sum += __shfl_xor(sum, off, 64);
        sq  += __shfl_xor(sq,  off, 64);
    }
    float mean = sum * (1.f / C_DIM);
    float var  = fmaxf(sq * (1.f / C_DIM) - mean * mean, 0.f);
    float rstd = rsqrtf(var + 1e-5f);
    float4 ga = ld4(g, lane * 4, isbf);
    float4 gb = ld4(g, 256 + lane * 4, isbf);
    float4 ba = ld4(b, lane * 4, isbf);
    float4 bb = ld4(b, 256 + lane * 4, isbf);
    ushort4 oa, ob;
    oa.x = f2bf((xa.x - mean) * rstd * ga.x + ba.x);
    oa.y = f2bf((xa.y - mean) * rstd * ga.y + ba.y);
    oa.z = f2bf((xa.z - mean) * rstd * ga.z + ba.z);
    oa.w = f2bf((xa.w - mean) * rstd * ga.w + ba.w);
    ob.x = f2bf((xb.x - mean) * rstd * gb.x + bb.x);
    ob.y = f2bf((xb.y - mean) * rstd * gb.y + bb.y);
    ob.z = f2bf((xb.z - mean) * rstd * gb.z + bb.z);
    ob.w = f2bf((xb.w - mean) * rstd * gb.w + bb.w);
    ((ushort4*)(h2 + (size_t)r * C_DIM))[lane]      = oa;
    ((ushort4*)(h2 + (size_t)r * C_DIM))[lane + 64] = ob;
}

// ---------------- generic bf16 MFMA GEMM: C = op(A @ B^T + bias) ----------------
#define GF_REMAP_A   1    // A row r -> (r/256)*512 + r%256 (compact patch -> full)
#define GF_GELU      2
#define GF_OUT_F32   4
#define GF_RES_F32   8    // += res (f32, [M][N])
#define GF_RES_PATCH 16   // += gathered patch token (raw dtype), valid positions only

__global__ __launch_bounds__(256) void gemm_kernel(
    const u16* __restrict__ A, const u16* __restrict__ BT,
    const void* __restrict__ bias,
    void* __restrict__ Cout, const void* __restrict__ resv,
    const int* __restrict__ flagp,
    int M, int N, int K, int flags, float alpha)
{
    __shared__ u16 As[128][72];   // 64 + 16B pad
    __shared__ u16 Bs[128][72];
    int isbf = *flagp;
    int tid = threadIdx.x;
    int m0 = blockIdx.y * 128, n0 = blockIdx.x * 128;
    int w = tid >> 6, lane = tid & 63;
    int wr = (w >> 1) * 64, wc = (w & 1) * 64;
    int l16 = lane & 15, quad = lane >> 4;

    f32x4 acc[4][4];
    #pragma unroll
    for (int i = 0; i < 4; i++)
        #pragma unroll
        for (int j = 0; j < 4; j++) { acc[i][j][0] = 0.f; acc[i][j][1] = 0.f; acc[i][j][2] = 0.f; acc[i][j][3] = 0.f; }

    for (int k0 = 0; k0 < K; k0 += 64) {
        #pragma unroll
        for (int it = 0; it < 4; it++) {
            int c = it * 256 + tid;            // 0..1023
            int row = c >> 3, kc = c & 7;
            int ar = m0 + row;
            if (flags & GF_REMAP_A) ar = ((ar >> 8) << 9) | (ar & 255);
            uint4 av = *(const uint4*)(A  + (size_t)ar * K + k0 + kc * 8);
            uint4 bv = *(const uint4*)(BT + (size_t)(n0 + row) * K + k0 + kc * 8);
            *(uint4*)&As[row][kc * 8] = av;
            *(uint4*)&Bs[row][kc * 8] = bv;
        }
        __syncthreads();
        #pragma unroll
        for (int ks = 0; ks < 2; ks++) {
            bf16x8 a[4], b[4];
            #pragma unroll
            for (int i = 0; i < 4; i++) a[i] = *(const bf16x8*)&As[wr + i * 16 + l16][ks * 32 + quad * 8];
            #pragma unroll
            for (int j = 0; j < 4; j++) b[j] = *(const bf16x8*)&Bs[wc + j * 16 + l16][ks * 32 + quad * 8];
            #pragma unroll
            for (int i = 0; i < 4; i++)
                #pragma unroll
                for (int j = 0; j < 4; j++)
                    acc[i][j] = __builtin_amdgcn_mfma_f32_16x16x32_bf16(a[i], b[j], acc[i][j], 0, 0, 0);
        }
        __syncthreads();
    }

    // epilogue
    #pragma unroll
    for (int i = 0; i < 4; i++) {
        int rowb = m0 + wr + i * 16 + quad * 4;
        #pragma unroll
        for (int j = 0; j < 4; j++) {
            int col = n0 + wc + j * 16 + l16;
            float bc = bias ? ldf(bias, col, isbf) : 0.f;
            #pragma unroll
            for (int r2 = 0; r2 < 4; r2++) {
                int row = rowb + r2;
                float v = (acc[i][j][r2] + bc) * alpha;
                if (flags & GF_GELU) v = 0.5f * v * (1.f + erff(v * 0.70710678118654752f));
                if (flags & GF_RES_F32) v += ((const float*)resv)[(size_t)row * N + col];
                if (flags & GF_RES_PATCH) {
                    int n = row >> 8, s = row & 255;
                    int iy = ((n >> 3) << 3) + (s >> 4);
                    int ix = ((n & 7) << 3) + (s & 15);
                    if (iy < P_DIM && ix < P_DIM)
                        v += ldf(resv, (size_t)(iy * P_DIM + ix) * C_DIM + col, isbf);
                }
                if (flags & GF_OUT_F32) ((float*)Cout)[(size_t)row * N + col] = v;
                else                    ((u16*)Cout)[(size_t)row * N + col]   = f2bf(v);
            }
        }
    }
}

// ---------------- flash attention per (window, head); patch queries only ----------------
__global__ __launch_bounds__(256) void attn_kernel(
    const u16* __restrict__ q, const u16* __restrict__ k, const u16* __restrict__ v,
    const unsigned char* __restrict__ validk,
    u16* __restrict__ o)
{
    __shared__ u16 kt[64][72];
    __shared__ u16 vt[64][72];      // transposed: vt[d][key]
    __shared__ u16 pt[4][64][72];   // per-wave P tile
    int h = blockIdx.x, n = blockIdx.y;
    int tid = threadIdx.x;
    int w = tid >> 6, lane = tid & 63;
    int l16 = lane & 15, quad = lane >> 4;

    bf16x8 qf[4][2];
    #pragma unroll
    for (int i = 0; i < 4; i++)
        #pragma unroll
        for (int ks = 0; ks < 2; ks++) {
            int row = n * A_TOK + w * 64 + i * 16 + l16;       // compact q
            int col = h * HDIM + ks * 32 + quad * 8;
            qf[i][ks] = *(const bf16x8*)(q + (size_t)row * C_DIM + col);
        }

    f32x4 oacc[4][4];
    float mrun[4][4], lrun[4][4];
    #pragma unroll
    for (int i = 0; i < 4; i++)
        #pragma unroll
        for (int j = 0; j < 4; j++) {
            oacc[i][j][0] = 0.f; oacc[i][j][1] = 0.f; oacc[i][j][2] = 0.f; oacc[i][j][3] = 0.f;
            mrun[i][j] = -1e30f; lrun[i][j] = 0.f;
        }

    for (int ktile = 0; ktile < 8; ktile++) {
        __syncthreads();
        #pragma unroll
        for (int it = 0; it < 2; it++) {
            int c = it * 256 + tid;         // 0..511
            int krow = c >> 3, dc = c & 7;
            int grow = n * S_TOK + ktile * 64 + krow;
            uint4 kv = *(const uint4*)(k + (size_t)grow * C_DIM + h * HDIM + dc * 8);
            *(uint4*)&kt[krow][dc * 8] = kv;
            uint4 vv = *(const uint4*)(v + (size_t)grow * C_DIM + h * HDIM + dc * 8);
            union { uint4 u; u16 s[8]; } tmp; tmp.u = vv;
            #pragma unroll
            for (int jj = 0; jj < 8; jj++) vt[dc * 8 + jj][krow] = tmp.s[jj];
        }
        __syncthreads();

        f32x4 sacc[4][4];
        #pragma unroll
        for (int i = 0; i < 4; i++)
            #pragma unroll
            for (int j = 0; j < 4; j++) { sacc[i][j][0] = 0.f; sacc[i][j][1] = 0.f; sacc[i][j][2] = 0.f; sacc[i][j][3] = 0.f; }
        #pragma unroll
        for (int ks = 0; ks < 2; ks++) {
            bf16x8 bfr[4];
            #pragma unroll
            for (int j = 0; j < 4; j++) bfr[j] = *(const bf16x8*)&kt[j * 16 + l16][ks * 32 + quad * 8];
            #pragma unroll
            for (int i = 0; i < 4; i++)
                #pragma unroll
                for (int j = 0; j < 4; j++)
                    sacc[i][j] = __builtin_amdgcn_mfma_f32_16x16x32_bf16(qf[i][ks], bfr[j], sacc[i][j], 0, 0, 0);
        }

        float kvalid[4];
        #pragma unroll
        for (int j = 0; j < 4; j++)
            kvalid[j] = validk[n * S_TOK + ktile * 64 + j * 16 + l16] ? 1.f : 0.f;

        #pragma unroll
        for (int i = 0; i < 4; i++) {
            #pragma unroll
            for (int r2 = 0; r2 < 4; r2++) {
                float sv0 = kvalid[0] > 0.f ? sacc[i][0][r2] : -1e30f;
                float sv1 = kvalid[1] > 0.f ? sacc[i][1][r2] : -1e30f;
                float sv2 = kvalid[2] > 0.f ? sacc[i][2][r2] : -1e30f;
                float sv3 = kvalid[3] > 0.f ? sacc[i][3][r2] : -1e30f;
                float tmax = fmaxf(fmaxf(sv0, sv1), fmaxf(sv2, sv3));
                #pragma unroll
                for (int off = 8; off; off >>= 1)
                    tmax = fmaxf(tmax, __shfl_xor(tmax, off, 64));
                float mnew = fmaxf(mrun[i][r2], tmax);
                float alp = __expf(fminf(mrun[i][r2] - mnew, 0.f));
                int prow = i * 16 + quad * 4 + r2;
                float psum = 0.f;
                #pragma unroll
                for (int j = 0; j < 4; j++) {
                    float p = (kvalid[j] > 0.f) ? __expf(fminf(sacc[i][j][r2] - mnew, 0.f)) : 0.f;
                    psum += p;
                    pt[w][prow][j * 16 + l16] = f2bf(p);
                }
                #pragma unroll
                for (int off = 8; off; off >>= 1)
                    psum += __shfl_xor(psum, off, 64);
                lrun[i][r2] = lrun[i][r2] * alp + psum;
                mrun[i][r2] = mnew;
                #pragma unroll
                for (int jd = 0; jd < 4; jd++) oacc[i][jd][r2] *= alp;
            }
        }
        __syncthreads();
        #pragma unroll
        for (int ks = 0; ks < 2; ks++) {
            bf16x8 pa[4], vb[4];
            #pragma unroll
            for (int i = 0; i < 4; i++)  pa[i]  = *(const bf16x8*)&pt[w][i * 16 + l16][ks * 32 + quad * 8];
            #pragma unroll
            for (int jd = 0; jd < 4; jd++) vb[jd] = *(const bf16x8*)&vt[jd * 16 + l16][ks * 32 + quad * 8];
            #pragma unroll
            for (int i = 0; i < 4; i++)
                #pragma unroll
                for (int jd = 0; jd < 4; jd++)
                    oacc[i][jd] = __builtin_amdgcn_mfma_f32_16x16x32_bf16(pa[i], vb[jd], oacc[i][jd], 0, 0, 0);
        }
    }

    #pragma unroll
    for (int i = 0; i < 4; i++) {
        #pragma unroll
        for (int r2 = 0; r2 < 4; r2++) {
            float inv = (lrun[i][r2] > 0.f) ? 1.f / lrun[i][r2] : 0.f;
            int row = n * A_TOK + w * 64 + i * 16 + quad * 4 + r2;
            #pragma unroll
            for (int jd = 0; jd < 4; jd++) {
                int col = h * HDIM + jd * 16 + l16;
                o[(size_t)row * C_DIM + col] = f2bf(oacc[i][jd][r2] * inv);
            }
        }
    }
}

// ---------------- final gather-average (replaces scatter/atomics) ----------------
__global__ __launch_bounds__(256) void gather_kernel(const float* __restrict__ xf,
                                                     void* __restrict__ out,
                                                     const int* __restrict__ flagp)
{
    int isbf = *flagp;
    int gid = blockIdx.x * 256 + threadIdx.x;    // pixel*128 + float4-chunk
    int p = gid >> 7, cv = gid & 127;
    int py = p >> 6, px = p & 63;
    float4 acc = make_float4(0.f, 0.f, 0.f, 0.f);
    int cnt = 0;
    #pragma unroll
    for (int dy = 0; dy < 2; dy++) {
        int y0 = ((py >> 3) - dy) << 3;
        if (y0 < 0) continue;
        #pragma unroll
        for (int dx = 0; dx < 2; dx++) {
            int x0 = ((px >> 3) - dx) << 3;
            if (x0 < 0) continue;
            int n = ((y0 >> 3) << 3) + (x0 >> 3);
            int s = (py - y0) * 16 + (px - x0);
            float4 t = ((const float4*)(xf + (size_t)(n * A_TOK + s) * C_DIM))[cv];
            acc.x += t.x; acc.y += t.y; acc.z += t.z; acc.w += t.w;
            cnt++;
        }
    }
    float inv = 1.f / (float)cnt;
    acc.x *= inv; acc.y *= inv; acc.z *= inv; acc.w *= inv;
    if (isbf) {
        ushort4 o;
        o.x = f2bf(acc.x); o.y = f2bf(acc.y); o.z = f2bf(acc.z); o.w = f2bf(acc.w);
        ((ushort4*)out)[gid] = o;
    } else {
        ((float4*)out)[gid] = acc;
    }
}

extern "C" void kernel_launch(void* const* d_in, const int* in_sizes, int n_in,
                              void* d_out, int out_size, void* d_ws, size_t ws_size,
                              hipStream_t stream)
{
    const void* patch = d_in[0];
    const void* vox   = d_in[1];
    const void* ln1g  = d_in[2];
    const void* ln1b  = d_in[3];
    const void* wq = d_in[4];  const void* bq = d_in[5];
    const void* wk = d_in[6];  const void* bk = d_in[7];
    const void* wv = d_in[8];  const void* bv = d_in[9];
    const void* wo = d_in[10]; const void* bo = d_in[11];
    const void* ln2g = d_in[12];
    const void* ln2b = d_in[13];
    const void* w1 = d_in[14]; const void* b1 = d_in[15];
    const void* w2 = d_in[16]; const void* b2 = d_in[17];
    const int* vpy = (const int*)d_in[18];
    const int* vpx = (const int*)d_in[19];

    const size_t MB = 1ull << 20;
    char* ws = (char*)d_ws;
    if (ws_size < 183 * MB) return;   // insufficient workspace -> visible failure

    u16*  hbuf  = (u16*)(ws + 0);          // [32768][512] bf16, 32MB
    u16*  kbuf  = (u16*)(ws + 32 * MB);    // 32MB
    u16*  vbuf  = (u16*)(ws + 64 * MB);    // 32MB
    u16*  qbuf  = (u16*)(ws + 96 * MB);    // [16384][512] bf16, 16MB (compact patch)
    u16*  obuf  = (u16*)(ws + 112 * MB);   // 16MB
    float* xbuf = (float*)(ws + 128 * MB); // [16384][512] f32, 32MB
    u16*  h2buf = (u16*)(ws + 160 * MB);   // 16MB
    u16*  tbuf  = (u16*)(ws + 0);          // [16384][2048] bf16, 64MB (reuse h+k, dead)
    float* xfbuf = (float*)(ws + 64 * MB); // 32MB (reuse v, dead)
    u16* wqT = (u16*)(ws + 176 * MB);
    u16* wkT = (u16*)(ws + 176 * MB + 512 * 1024);
    u16* wvT = (u16*)(ws + 177 * MB);
    u16* woT = (u16*)(ws + 177 * MB + 512 * 1024);
    u16* w1T = (u16*)(ws + 178 * MB);      // [2048][512], 2MB
    u16* w2T = (u16*)(ws + 180 * MB);      // [512][2048], 2MB
    int* sel = (int*)(ws + 182 * MB);      // 64KB
    unsigned char* validk = (unsigned char*)(ws + 182 * MB + 64 * 1024); // 32KB
    int* flagp = (int*)(ws + 182 * MB + 128 * 1024);

    detect_kernel<<<1, 256, 0, stream>>>((const u32*)patch, flagp);

    dim3 blkT(32, 8);
    wtrans_kernel<<<dim3(16, 16), blkT, 0, stream>>>(wq, wqT, 512, 512, flagp);
    wtrans_kernel<<<dim3(16, 16), blkT, 0, stream>>>(wk, wkT, 512, 512, flagp);
    wtrans_kernel<<<dim3(16, 16), blkT, 0, stream>>>(wv, wvT, 512, 512, flagp);
    wtrans_kernel<<<dim3(16, 16), blkT, 0, stream>>>(wo, woT, 512, 512, flagp);
    wtrans_kernel<<<dim3(64, 16), blkT, 0, stream>>>(w1, w1T, 512, 2048, flagp);
    wtrans_kernel<<<dim3(16, 64), blkT, 0, stream>>>(w2, w2T, 2048, 512, flagp);

    voxsel_kernel<<<NWIN, 64, 0, stream>>>(vpy, vpx, sel);
    ln1_kernel<<<NROW / 4, 256, 0, stream>>>(patch, vox, ln1g, ln1b, sel, flagp, hbuf, validk);

    // q only for patch rows (compact), scale folded in; k/v for all rows
    gemm_kernel<<<dim3(4, NPATCH / 128), 256, 0, stream>>>(hbuf, wqT, bq, qbuf, nullptr, flagp,
        NPATCH, 512, 512, GF_REMAP_A, 0.125f);
    gemm_kernel<<<dim3(4, NROW / 128), 256, 0, stream>>>(hbuf, wkT, bk, kbuf, nullptr, flagp,
        NROW, 512, 512, 0, 1.f);
    gemm_kernel<<<dim3(4, NROW / 128), 256, 0, stream>>>(hbuf, wvT, bv, vbuf, nullptr, flagp,
        NROW, 512, 512, 0, 1.f);

    attn_kernel<<<dim3(HEADS, NWIN), 256, 0, stream>>>(qbuf, kbuf, vbuf, validk, obuf);

    // x = tokens(patch gather) + o @ wo + bo   (f32)
    gemm_kernel<<<dim3(4, NPATCH / 128), 256, 0, stream>>>(obuf, woT, bo, xbuf, patch, flagp,
        NPATCH, 512, 512, GF_OUT_F32 | GF_RES_PATCH, 1.f);

    ln2_kernel<<<NPATCH / 4, 256, 0, stream>>>(xbuf, ln2g, ln2b, flagp, h2buf);

    gemm_kernel<<<dim3(16, NPATCH / 128), 256, 0, stream>>>(h2buf, w1T, b1, tbuf, nullptr, flagp,
        NPATCH, 2048, 512, GF_GELU, 1.f);
    gemm_kernel<<<dim3(4, NPATCH / 128), 256, 0, stream>>>(tbuf, w2T, b2, xfbuf, xbuf, flagp,
        NPATCH, 512, 2048, GF_OUT_F32 | GF_RES_F32, 1.f);

    gather_kernel<<<(4096 * 128) / 256, 256, 0, stream>>>(xfbuf, d_out, flagp);
}

// Round 3
// 564.252 us; speedup vs baseline: 1.0798x; 1.0798x over previous
//
#include <hip/hip_runtime.h>
#include <math.h>

using u16 = unsigned short;
using u32 = unsigned int;
using u64 = unsigned long long;
using bf16x8 = __attribute__((ext_vector_type(8))) short;
using f32x4  = __attribute__((ext_vector_type(4))) float;

#define C_DIM   512
#define HEADS   8
#define HDIM    64
#define P_DIM   64
#define A_TOK   256
#define VCAP    256
#define S_TOK   512
#define NWIN    64
#define NROW    32768      // NWIN * S_TOK
#define NPATCH  16384      // NWIN * A_TOK
#define MLP_DIM 2048
#define NV_TOT  2048

__device__ __forceinline__ float bf2f(u16 b) { return __uint_as_float(((u32)b) << 16); }
__device__ __forceinline__ u16 f2bf(float f) {
    u32 u = __float_as_uint(f);
    return (u16)((u + 0x7fffu + ((u >> 16) & 1u)) >> 16);   // RNE
}
__device__ __forceinline__ float4 bf4f(ushort4 v) {
    return make_float4(bf2f(v.x), bf2f(v.y), bf2f(v.z), bf2f(v.w));
}
// dtype-agnostic loads from RAW inputs: isbf=1 -> bf16, else f32
__device__ __forceinline__ float ldf(const void* p, size_t e, int isbf) {
    return isbf ? bf2f(((const u16*)p)[e]) : ((const float*)p)[e];
}
__device__ __forceinline__ float4 ld4(const void* p, size_t e, int isbf) {  // e % 4 == 0
    if (isbf) return bf4f(*(const ushort4*)((const u16*)p + e));
    return *(const float4*)((const float*)p + e);
}
// async global->LDS, 16B per lane; lds dest must be wave-uniform-base + lane*16
__device__ __forceinline__ void gload16(const u16* g, u16* l) {
    __builtin_amdgcn_global_load_lds(
        (const __attribute__((address_space(1))) u32*)g,
        (__attribute__((address_space(3))) u32*)l, 16, 0, 0);
}

// ---------------- dtype detector: vote on low-16-bits-as-bf16 plausibility ----------------
__global__ void detect_kernel(const u32* __restrict__ patch, int* __restrict__ flag)
{
    __shared__ int sm[256];
    int t = threadIdx.x;
    int cnt = 0;
    for (int i = t; i < 4096; i += 256) {
        u32 w = patch[i];
        float v = __uint_as_float((w & 0xffffu) << 16);
        float a = fabsf(v);
        if (a > 1e-8f && a < 1e4f) cnt++;
    }
    sm[t] = cnt;
    __syncthreads();
    for (int o = 128; o; o >>= 1) { if (t < o) sm[t] += sm[t + o]; __syncthreads(); }
    if (t == 0) *flag = (sm[0] > 2458) ? 1 : 0;    // >60% plausible => bf16 world
}

// ---------------- weight transpose: in [K][N] -> out [N][K] bf16 ----------------
__global__ void wtrans_kernel(const void* __restrict__ in, u16* __restrict__ out,
                              int K, int N, const int* __restrict__ flagp)
{
    __shared__ u16 tile[32][33];
    int isbf = *flagp;
    int n0 = blockIdx.x * 32, k0 = blockIdx.y * 32;
    int tx = threadIdx.x, ty = threadIdx.y;   // block (32, 8)
    #pragma unroll
    for (int i = 0; i < 4; i++)
        tile[ty + i * 8][tx] = f2bf(ldf(in, (size_t)(k0 + ty + i * 8) * N + (n0 + tx), isbf));
    __syncthreads();
    #pragma unroll
    for (int i = 0; i < 4; i++)
        out[(size_t)(n0 + ty + i * 8) * K + (k0 + tx)] = tile[tx][ty + i * 8];
}

// ---------------- per-window voxel selection (stable order, cap 256) ----------------
__global__ void voxsel_kernel(const int* __restrict__ vy, const int* __restrict__ vx,
                              int* __restrict__ sel)
{
    int n = blockIdx.x;                 // 64 windows, 64 threads (1 wave)
    int lane = threadIdx.x;
    int y0 = (n >> 3) << 3, x0 = (n & 7) << 3;
    int count = 0;
    for (int base = 0; base < NV_TOT; base += 64) {
        int v = base + lane;
        int yy = vy[v], xx = vx[v];
        bool m = (yy >= y0) && (yy < y0 + 16) && (xx >= x0) && (xx < x0 + 16);
        u64 mask = __ballot(m);
        int pos = count + __popcll(mask & ((1ull << lane) - 1ull));
        if (m && pos < VCAP) sel[n * VCAP + pos] = v;
        count += __popcll(mask);
    }
    for (int j = lane; j < VCAP; j += 64)
        if (j >= count) sel[n * VCAP + j] = -1;
}

// ---------------- gather tokens + LN1 -> h (bf16), validity flags ----------------
__global__ __launch_bounds__(256) void ln1_kernel(
    const void* __restrict__ patch, const void* __restrict__ vox,
    const void* __restrict__ g, const void* __restrict__ b,
    const int* __restrict__ sel, const int* __restrict__ flagp,
    u16* __restrict__ h, unsigned char* __restrict__ validk)
{
    int isbf = *flagp;
    int r = blockIdx.x * 4 + (threadIdx.x >> 6);    // one wave per row
    int lane = threadIdx.x & 63;
    int n = r >> 9, s = r & 511;
    const void* tok = nullptr;
    size_t base = 0;
    bool valid;
    if (s < A_TOK) {
        int wy = s >> 4, wx = s & 15;
        int iy = ((n >> 3) << 3) + wy, ix = ((n & 7) << 3) + wx;
        valid = (iy < P_DIM) && (ix < P_DIM);
        tok = patch; base = (size_t)(iy * P_DIM + ix) * C_DIM;
    } else {
        int idx = sel[n * VCAP + (s - A_TOK)];
        valid = (idx >= 0);
        tok = vox; base = valid ? (size_t)idx * C_DIM : 0;
    }
    float4 xa = make_float4(0.f, 0.f, 0.f, 0.f), xb = xa;
    if (valid) {
        xa = ld4(tok, base + lane * 4, isbf);
        xb = ld4(tok, base + 256 + lane * 4, isbf);
    }
    float sum = xa.x + xa.y + xa.z + xa.w + xb.x + xb.y + xb.z + xb.w;
    float sq  = xa.x * xa.x + xa.y * xa.y + xa.z * xa.z + xa.w * xa.w
              + xb.x * xb.x + xb.y * xb.y + xb.z * xb.z + xb.w * xb.w;
    #pragma unroll
    for (int off = 32; off; off >>= 1) {
        sum += __shfl_xor(sum, off, 64);
        sq  += __shfl_xor(sq,  off, 64);
    }
    float mean = sum * (1.f / C_DIM);
    float var  = fmaxf(sq * (1.f / C_DIM) - mean * mean, 0.f);
    float rstd = rsqrtf(var + 1e-5f);
    float4 ga = ld4(g, lane * 4, isbf);
    float4 gb = ld4(g, 256 + lane * 4, isbf);
    float4 ba = ld4(b, lane * 4, isbf);
    float4 bb = ld4(b, 256 + lane * 4, isbf);
    ushort4 oa, ob;
    oa.x = f2bf((xa.x - mean) * rstd * ga.x + ba.x);
    oa.y = f2bf((xa.y - mean) * rstd * ga.y + ba.y);
    oa.z = f2bf((xa.z - mean) * rstd * ga.z + ba.z);
    oa.w = f2bf((xa.w - mean) * rstd * ga.w + ba.w);
    ob.x = f2bf((xb.x - mean) * rstd * gb.x + bb.x);
    ob.y = f2bf((xb.y - mean) * rstd * gb.y + bb.y);
    ob.z = f2bf((xb.z - mean) * rstd * gb.z + bb.z);
    ob.w = f2bf((xb.w - mean) * rstd * gb.w + bb.w);
    ((ushort4*)(h + (size_t)r * C_DIM))[lane]      = oa;
    ((ushort4*)(h + (size_t)r * C_DIM))[lane + 64] = ob;
    if (lane == 0) validk[r] = valid ? 1 : 0;
}

// ---------------- LN2 over f32 rows -> bf16 ----------------
__global__ __launch_bounds__(256) void ln2_kernel(
    const float* __restrict__ x,
    const void* __restrict__ g, const void* __restrict__ b,
    const int* __restrict__ flagp,
    u16* __restrict__ h2)
{
    int isbf = *flagp;
    int r = blockIdx.x * 4 + (threadIdx.x >> 6);
    int lane = threadIdx.x & 63;
    const float* src = x + (size_t)r * C_DIM;
    float4 xa = ((const float4*)src)[lane];
    float4 xb = ((const float4*)src)[lane + 64];
    float sum = xa.x + xa.y + xa.z + xa.w + xb.x + xb.y + xb.z + xb.w;
    float sq  = xa.x * xa.x + xa.y * xa.y + xa.z * xa.z + xa.w * xa.w
              + xb.x * xb.x + xb.y * xb.y + xb.z * xb.z + xb.w * xb.w;
    #pragma unroll
    for (int off = 32; off; off >>= 1) {
        sum += __shfl_xor(sum, off, 64);
        sq  += __shfl_xor(sq,  off, 64);
    }
    float mean = sum * (1.f / C_DIM);
    float var  = fmaxf(sq * (1.f / C_DIM) - mean * mean, 0.f);
    float rstd = rsqrtf(var + 1e-5f);
    float4 ga = ld4(g, lane * 4, isbf);
    float4 gb = ld4(g, 256 + lane * 4, isbf);
    float4 ba = ld4(b, lane * 4, isbf);
    float4 bb = ld4(b, 256 + lane * 4, isbf);
    ushort4 oa, ob;
    oa.x = f2bf((xa.x - mean) * rstd * ga.x + ba.x);
    oa.y = f2bf((xa.y - mean) * rstd * ga.y + ba.y);
    oa.z = f2bf((xa.z - mean) * rstd * ga.z + ba.z);
    oa.w = f2bf((xa.w - mean) * rstd * ga.w + ba.w);
    ob.x = f2bf((xb.x - mean) * rstd * gb.x + bb.x);
    ob.y = f2bf((xb.y - mean) * rstd * gb.y + bb.y);
    ob.z = f2bf((xb.z - mean) * rstd * gb.z + bb.z);
    ob.w = f2bf((xb.w - mean) * rstd * gb.w + bb.w);
    ((ushort4*)(h2 + (size_t)r * C_DIM))[lane]      = oa;
    ((ushort4*)(h2 + (size_t)r * C_DIM))[lane + 64] = ob;
}

// ---------------- generic bf16 MFMA GEMM: C = op(A @ B^T + bias) ----------------
#define GF_REMAP_A   1    // A row r -> (r/256)*512 + r%256 (compact patch -> full)
#define GF_GELU      2
#define GF_OUT_F32   4
#define GF_RES_F32   8    // += res (f32, [M][N])
#define GF_RES_PATCH 16   // += gathered patch token (raw dtype), valid positions only

__global__ __launch_bounds__(256) void gemm_kernel(
    const u16* __restrict__ A, const u16* __restrict__ BT,
    const void* __restrict__ bias,
    void* __restrict__ Cout, const void* __restrict__ resv,
    const int* __restrict__ flagp,
    int M, int N, int K, int flags, float alpha)
{
    __shared__ u16 As[128 * 64];   // unpadded: global_load_lds layout (m97 structure)
    __shared__ u16 Bs[128 * 64];
    int isbf = *flagp;
    int tid = threadIdx.x;
    int m0 = blockIdx.y * 128, n0 = blockIdx.x * 128;
    int w = tid >> 6, lane = tid & 63;
    int wr = (w >> 1) * 64, wc = (w & 1) * 64;
    int l16 = lane & 15, quad = lane >> 4;

    f32x4 acc[4][4];
    #pragma unroll
    for (int i = 0; i < 4; i++)
        #pragma unroll
        for (int j = 0; j < 4; j++) { acc[i][j][0] = 0.f; acc[i][j][1] = 0.f; acc[i][j][2] = 0.f; acc[i][j][3] = 0.f; }

    for (int k0 = 0; k0 < K; k0 += 64) {
        #pragma unroll
        for (int it = 0; it < 4; it++) {
            int c = (it * 4 + w) * 64 + lane;   // 0..1023; 8 lanes per 64-elem row
            int row = c >> 3, kc = c & 7;
            int ar = m0 + row;
            if (flags & GF_REMAP_A) ar = ((ar >> 8) << 9) | (ar & 255);
            gload16(A  + (size_t)ar * K + k0 + kc * 8,        As + (size_t)c * 8);
            gload16(BT + (size_t)(n0 + row) * K + k0 + kc * 8, Bs + (size_t)c * 8);
        }
        __syncthreads();
        #pragma unroll
        for (int ks = 0; ks < 2; ks++) {
            bf16x8 a[4], b[4];
            #pragma unroll
            for (int i = 0; i < 4; i++) a[i] = *(const bf16x8*)&As[(wr + i * 16 + l16) * 64 + ks * 32 + quad * 8];
            #pragma unroll
            for (int j = 0; j < 4; j++) b[j] = *(const bf16x8*)&Bs[(wc + j * 16 + l16) * 64 + ks * 32 + quad * 8];
            #pragma unroll
            for (int i = 0; i < 4; i++)
                #pragma unroll
                for (int j = 0; j < 4; j++)
                    acc[i][j] = __builtin_amdgcn_mfma_f32_16x16x32_bf16(a[i], b[j], acc[i][j], 0, 0, 0);
        }
        __syncthreads();
    }

    // epilogue
    #pragma unroll
    for (int i = 0; i < 4; i++) {
        int rowb = m0 + wr + i * 16 + quad * 4;
        #pragma unroll
        for (int j = 0; j < 4; j++) {
            int col = n0 + wc + j * 16 + l16;
            float bc = bias ? ldf(bias, col, isbf) : 0.f;
            #pragma unroll
            for (int r2 = 0; r2 < 4; r2++) {
                int row = rowb + r2;
                float v = (acc[i][j][r2] + bc) * alpha;
                if (flags & GF_GELU) v = 0.5f * v * (1.f + erff(v * 0.70710678118654752f));
                if (flags & GF_RES_F32) v += ((const float*)resv)[(size_t)row * N + col];
                if (flags & GF_RES_PATCH) {
                    int n = row >> 8, s = row & 255;
                    int iy = ((n >> 3) << 3) + (s >> 4);
                    int ix = ((n & 7) << 3) + (s & 15);
                    if (iy < P_DIM && ix < P_DIM)
                        v += ldf(resv, (size_t)(iy * P_DIM + ix) * C_DIM + col, isbf);
                }
                if (flags & GF_OUT_F32) ((float*)Cout)[(size_t)row * N + col] = v;
                else                    ((u16*)Cout)[(size_t)row * N + col]   = f2bf(v);
            }
        }
    }
}

// ---------------- flash attention per (window, head); patch queries only ----------------
// Scores are bounded (|s| <~ 6: unit-variance q,k, 1/8 scale folded into q), so we use
// exp(s) with NO max-shift: removes all per-tile cross-lane reduces and O rescaling.
// Row-sum is accumulated per-lane and reduced once at the end.
__global__ __launch_bounds__(256) void attn_kernel(
    const u16* __restrict__ q, const u16* __restrict__ k, const u16* __restrict__ v,
    const unsigned char* __restrict__ validk,
    u16* __restrict__ o)
{
    __shared__ u16 kt[64 * 64];          // unpadded (async-staged), row-major [key][d]
    __shared__ u16 vt[64 * 68];          // transposed [d][key], pad 68 (stride 34 dw)
    __shared__ u16 pt[4 * 64 * 68];      // per-wave P tile, pad 68
    int h = blockIdx.x, n = blockIdx.y;
    int tid = threadIdx.x;
    int w = tid >> 6, lane = tid & 63;
    int l16 = lane & 15, quad = lane >> 4;

    bf16x8 qf[4][2];
    #pragma unroll
    for (int i = 0; i < 4; i++)
        #pragma unroll
        for (int ks = 0; ks < 2; ks++) {
            int row = n * A_TOK + w * 64 + i * 16 + l16;       // compact q
            int col = h * HDIM + ks * 32 + quad * 8;
            qf[i][ks] = *(const bf16x8*)(q + (size_t)row * C_DIM + col);
        }

    f32x4 oacc[4][4];
    float lsum[4][4];
    #pragma unroll
    for (int i = 0; i < 4; i++)
        #pragma unroll
        for (int j = 0; j < 4; j++) {
            oacc[i][j][0] = 0.f; oacc[i][j][1] = 0.f; oacc[i][j][2] = 0.f; oacc[i][j][3] = 0.f;
            lsum[i][j] = 0.f;
        }

    for (int ktile = 0; ktile < 8; ktile++) {
        __syncthreads();                       // prior PV readers done before overwrite
        // K tile: async direct-to-LDS (contiguous layout)
        #pragma unroll
        for (int it = 0; it < 2; it++) {
            int c = (it * 4 + w) * 64 + lane;  // 0..511
            int krow = c >> 3, dc = c & 7;
            int grow = n * S_TOK + ktile * 64 + krow;
            gload16(k + (size_t)grow * C_DIM + h * HDIM + dc * 8, kt + (size_t)c * 8);
        }
        // V tile: register transpose -> vt[d][key]
        #pragma unroll
        for (int it = 0; it < 2; it++) {
            int c = it * 256 + tid;
            int krow = c >> 3, dc = c & 7;
            int grow = n * S_TOK + ktile * 64 + krow;
            uint4 vv = *(const uint4*)(v + (size_t)grow * C_DIM + h * HDIM + dc * 8);
            union { uint4 u; u16 s[8]; } tmp; tmp.u = vv;
            #pragma unroll
            for (int jj = 0; jj < 8; jj++) vt[(dc * 8 + jj) * 68 + krow] = tmp.s[jj];
        }
        __syncthreads();

        f32x4 sacc[4][4];
        #pragma unroll
        for (int i = 0; i < 4; i++)
            #pragma unroll
            for (int j = 0; j < 4; j++) { sacc[i][j][0] = 0.f; sacc[i][j][1] = 0.f; sacc[i][j][2] = 0.f; sacc[i][j][3] = 0.f; }
        #pragma unroll
        for (int ks = 0; ks < 2; ks++) {
            bf16x8 bfr[4];
            #pragma unroll
            for (int j = 0; j < 4; j++) bfr[j] = *(const bf16x8*)&kt[(j * 16 + l16) * 64 + ks * 32 + quad * 8];
            #pragma unroll
            for (int i = 0; i < 4; i++)
                #pragma unroll
                for (int j = 0; j < 4; j++)
                    sacc[i][j] = __builtin_amdgcn_mfma_f32_16x16x32_bf16(qf[i][ks], bfr[j], sacc[i][j], 0, 0, 0);
        }

        bool kvalid[4];
        #pragma unroll
        for (int j = 0; j < 4; j++)
            kvalid[j] = validk[n * S_TOK + ktile * 64 + j * 16 + l16] != 0;

        // p = exp(s) (no shift), accumulate per-lane row-sum, stash P tile (per-wave)
        #pragma unroll
        for (int i = 0; i < 4; i++)
            #pragma unroll
            for (int r2 = 0; r2 < 4; r2++) {
                int prow = i * 16 + quad * 4 + r2;
                #pragma unroll
                for (int j = 0; j < 4; j++) {
                    float p = kvalid[j] ? __expf(sacc[i][j][r2]) : 0.f;
                    lsum[i][r2] += p;
                    pt[(w * 64 + prow) * 68 + j * 16 + l16] = f2bf(p);
                }
            }
        // pt is per-wave: same-wave LDS ops are in-order, no barrier needed.
        asm volatile("" ::: "memory");   // forbid compiler reordering read-before-write
        #pragma unroll
        for (int ks = 0; ks < 2; ks++) {
            bf16x8 pa[4], vb[4];
            #pragma unroll
            for (int i = 0; i < 4; i++)   pa[i]  = *(const bf16x8*)&pt[(w * 64 + i * 16 + l16) * 68 + ks * 32 + quad * 8];
            #pragma unroll
            for (int jd = 0; jd < 4; jd++) vb[jd] = *(const bf16x8*)&vt[(jd * 16 + l16) * 68 + ks * 32 + quad * 8];
            #pragma unroll
            for (int i = 0; i < 4; i++)
                #pragma unroll
                for (int jd = 0; jd < 4; jd++)
                    oacc[i][jd] = __builtin_amdgcn_mfma_f32_16x16x32_bf16(pa[i], vb[jd], oacc[i][jd], 0, 0, 0);
        }
    }

    #pragma unroll
    for (int i = 0; i < 4; i++) {
        #pragma unroll
        for (int r2 = 0; r2 < 4; r2++) {
            float l = lsum[i][r2];
            #pragma unroll
            for (int off = 8; off; off >>= 1)
                l += __shfl_xor(l, off, 64);
            float inv = (l > 0.f) ? 1.f / l : 0.f;
            int row = n * A_TOK + w * 64 + i * 16 + quad * 4 + r2;
            #pragma unroll
            for (int jd = 0; jd < 4; jd++) {
                int col = h * HDIM + jd * 16 + l16;
                o[(size_t)row * C_DIM + col] = f2bf(oacc[i][jd][r2] * inv);
            }
        }
    }
}

// ---------------- final gather-average (replaces scatter/atomics) ----------------
__global__ __launch_bounds__(256) void gather_kernel(const float* __restrict__ xf,
                                                     void* __restrict__ out,
                                                     const int* __restrict__ flagp)
{
    int isbf = *flagp;
    int gid = blockIdx.x * 256 + threadIdx.x;    // pixel*128 + float4-chunk
    int p = gid >> 7, cv = gid & 127;
    int py = p >> 6, px = p & 63;
    float4 acc = make_float4(0.f, 0.f, 0.f, 0.f);
    int cnt = 0;
    #pragma unroll
    for (int dy = 0; dy < 2; dy++) {
        int y0 = ((py >> 3) - dy) << 3;
        if (y0 < 0) continue;
        #pragma unroll
        for (int dx = 0; dx < 2; dx++) {
            int x0 = ((px >> 3) - dx) << 3;
            if (x0 < 0) continue;
            int n = ((y0 >> 3) << 3) + (x0 >> 3);
            int s = (py - y0) * 16 + (px - x0);
            float4 t = ((const float4*)(xf + (size_t)(n * A_TOK + s) * C_DIM))[cv];
            acc.x += t.x; acc.y += t.y; acc.z += t.z; acc.w += t.w;
            cnt++;
        }
    }
    float inv = 1.f / (float)cnt;
    acc.x *= inv; acc.y *= inv; acc.z *= inv; acc.w *= inv;
    if (isbf) {
        ushort4 o;
        o.x = f2bf(acc.x); o.y = f2bf(acc.y); o.z = f2bf(acc.z); o.w = f2bf(acc.w);
        ((ushort4*)out)[gid] = o;
    } else {
        ((float4*)out)[gid] = acc;
    }
}

extern "C" void kernel_launch(void* const* d_in, const int* in_sizes, int n_in,
                              void* d_out, int out_size, void* d_ws, size_t ws_size,
                              hipStream_t stream)
{
    const void* patch = d_in[0];
    const void* vox   = d_in[1];
    const void* ln1g  = d_in[2];
    const void* ln1b  = d_in[3];
    const void* wq = d_in[4];  const void* bq = d_in[5];
    const void* wk = d_in[6];  const void* bk = d_in[7];
    const void* wv = d_in[8];  const void* bv = d_in[9];
    const void* wo = d_in[10]; const void* bo = d_in[11];
    const void* ln2g = d_in[12];
    const void* ln2b = d_in[13];
    const void* w1 = d_in[14]; const void* b1 = d_in[15];
    const void* w2 = d_in[16]; const void* b2 = d_in[17];
    const int* vpy = (const int*)d_in[18];
    const int* vpx = (const int*)d_in[19];

    const size_t MB = 1ull << 20;
    char* ws = (char*)d_ws;
    if (ws_size < 183 * MB) return;   // insufficient workspace -> visible failure

    u16*  hbuf  = (u16*)(ws + 0);          // [32768][512] bf16, 32MB
    u16*  kbuf  = (u16*)(ws + 32 * MB);    // 32MB
    u16*  vbuf  = (u16*)(ws + 64 * MB);    // 32MB
    u16*  qbuf  = (u16*)(ws + 96 * MB);    // [16384][512] bf16, 16MB (compact patch)
    u16*  obuf  = (u16*)(ws + 112 * MB);   // 16MB
    float* xbuf = (float*)(ws + 128 * MB); // [16384][512] f32, 32MB
    u16*  h2buf = (u16*)(ws + 160 * MB);   // 16MB
    u16*  tbuf  = (u16*)(ws + 0);          // [16384][2048] bf16, 64MB (reuse h+k, dead)
    float* xfbuf = (float*)(ws + 64 * MB); // 32MB (reuse v, dead)
    u16* wqT = (u16*)(ws + 176 * MB);
    u16* wkT = (u16*)(ws + 176 * MB + 512 * 1024);
    u16* wvT = (u16*)(ws + 177 * MB);
    u16* woT = (u16*)(ws + 177 * MB + 512 * 1024);
    u16* w1T = (u16*)(ws + 178 * MB);      // [2048][512], 2MB
    u16* w2T = (u16*)(ws + 180 * MB);      // [512][2048], 2MB
    int* sel = (int*)(ws + 182 * MB);      // 64KB
    unsigned char* validk = (unsigned char*)(ws + 182 * MB + 64 * 1024); // 32KB
    int* flagp = (int*)(ws + 182 * MB + 128 * 1024);

    detect_kernel<<<1, 256, 0, stream>>>((const u32*)patch, flagp);

    dim3 blkT(32, 8);
    wtrans_kernel<<<dim3(16, 16), blkT, 0, stream>>>(wq, wqT, 512, 512, flagp);
    wtrans_kernel<<<dim3(16, 16), blkT, 0, stream>>>(wk, wkT, 512, 512, flagp);
    wtrans_kernel<<<dim3(16, 16), blkT, 0, stream>>>(wv, wvT, 512, 512, flagp);
    wtrans_kernel<<<dim3(16, 16), blkT, 0, stream>>>(wo, woT, 512, 512, flagp);
    wtrans_kernel<<<dim3(64, 16), blkT, 0, stream>>>(w1, w1T, 512, 2048, flagp);
    wtrans_kernel<<<dim3(16, 64), blkT, 0, stream>>>(w2, w2T, 2048, 512, flagp);

    voxsel_kernel<<<NWIN, 64, 0, stream>>>(vpy, vpx, sel);
    ln1_kernel<<<NROW / 4, 256, 0, stream>>>(patch, vox, ln1g, ln1b, sel, flagp, hbuf, validk);

    // q only for patch rows (compact), scale folded in; k/v for all rows
    gemm_kernel<<<dim3(4, NPATCH / 128), 256, 0, stream>>>(hbuf, wqT, bq, qbuf, nullptr, flagp,
        NPATCH, 512, 512, GF_REMAP_A, 0.125f);
    gemm_kernel<<<dim3(4, NROW / 128), 256, 0, stream>>>(hbuf, wkT, bk, kbuf, nullptr, flagp,
        NROW, 512, 512, 0, 1.f);
    gemm_kernel<<<dim3(4, NROW / 128), 256, 0, stream>>>(hbuf, wvT, bv, vbuf, nullptr, flagp,
        NROW, 512, 512, 0, 1.f);

    attn_kernel<<<dim3(HEADS, NWIN), 256, 0, stream>>>(qbuf, kbuf, vbuf, validk, obuf);

    // x = tokens(patch gather) + o @ wo + bo   (f32)
    gemm_kernel<<<dim3(4, NPATCH / 128), 256, 0, stream>>>(obuf, woT, bo, xbuf, patch, flagp,
        NPATCH, 512, 512, GF_OUT_F32 | GF_RES_PATCH, 1.f);

    ln2_kernel<<<NPATCH / 4, 256, 0, stream>>>(xbuf, ln2g, ln2b, flagp, h2buf);

    gemm_kernel<<<dim3(16, NPATCH / 128), 256, 0, stream>>>(h2buf, w1T, b1, tbuf, nullptr, flagp,
        NPATCH, 2048, 512, GF_GELU, 1.f);
    gemm_kernel<<<dim3(4, NPATCH / 128), 256, 0, stream>>>(tbuf, w2T, b2, xfbuf, xbuf, flagp,
        NPATCH, 512, 2048, GF_OUT_F32 | GF_RES_F32, 1.f);

    gather_kernel<<<(4096 * 128) / 256, 256, 0, stream>>>(xfbuf, d_out, flagp);
}

// Round 4
// 544.775 us; speedup vs baseline: 1.1184x; 1.0358x over previous
//
#include <hip/hip_runtime.h>
#include <math.h>

using u16 = unsigned short;
using u32 = unsigned int;
using u64 = unsigned long long;
using bf16x8 = __attribute__((ext_vector_type(8))) short;
using f32x4  = __attribute__((ext_vector_type(4))) float;

#define C_DIM   512
#define HEADS   8
#define HDIM    64
#define P_DIM   64
#define A_TOK   256
#define VCAP    256
#define S_TOK   512
#define NWIN    64
#define NROW    32768      // NWIN * S_TOK
#define NPATCH  16384      // NWIN * A_TOK
#define MLP_DIM 2048
#define NV_TOT  2048

__device__ __forceinline__ float bf2f(u16 b) { return __uint_as_float(((u32)b) << 16); }
__device__ __forceinline__ u16 f2bf(float f) {
    u32 u = __float_as_uint(f);
    return (u16)((u + 0x7fffu + ((u >> 16) & 1u)) >> 16);   // RNE
}
__device__ __forceinline__ float4 bf4f(ushort4 v) {
    return make_float4(bf2f(v.x), bf2f(v.y), bf2f(v.z), bf2f(v.w));
}
// dtype-agnostic loads from RAW inputs: isbf=1 -> bf16, else f32
__device__ __forceinline__ float ldf(const void* p, size_t e, int isbf) {
    return isbf ? bf2f(((const u16*)p)[e]) : ((const float*)p)[e];
}
__device__ __forceinline__ float4 ld4(const void* p, size_t e, int isbf) {  // e % 4 == 0
    if (isbf) return bf4f(*(const ushort4*)((const u16*)p + e));
    return *(const float4*)((const float*)p + e);
}
// async global->LDS, 16B per lane; lds dest must be wave-uniform-base + lane*16
__device__ __forceinline__ void gload16(const u16* g, u16* l) {
    __builtin_amdgcn_global_load_lds(
        (const __attribute__((address_space(1))) u32*)g,
        (__attribute__((address_space(3))) u32*)l, 16, 0, 0);
}

// ---------------- dtype detector: vote on low-16-bits-as-bf16 plausibility ----------------
__global__ void detect_kernel(const u32* __restrict__ patch, int* __restrict__ flag)
{
    __shared__ int sm[256];
    int t = threadIdx.x;
    int cnt = 0;
    for (int i = t; i < 4096; i += 256) {
        u32 w = patch[i];
        float v = __uint_as_float((w & 0xffffu) << 16);
        float a = fabsf(v);
        if (a > 1e-8f && a < 1e4f) cnt++;
    }
    sm[t] = cnt;
    __syncthreads();
    for (int o = 128; o; o >>= 1) { if (t < o) sm[t] += sm[t + o]; __syncthreads(); }
    if (t == 0) *flag = (sm[0] > 2458) ? 1 : 0;    // >60% plausible => bf16 world
}

// ---------------- weight transpose: in [K][N] -> out [N][K] bf16, optional scale ------------
__global__ void wtrans_kernel(const void* __restrict__ in, u16* __restrict__ out,
                              int K, int N, const int* __restrict__ flagp, float scale)
{
    __shared__ u16 tile[32][33];
    int isbf = *flagp;
    int n0 = blockIdx.x * 32, k0 = blockIdx.y * 32;
    int tx = threadIdx.x, ty = threadIdx.y;   // block (32, 8)
    #pragma unroll
    for (int i = 0; i < 4; i++)
        tile[ty + i * 8][tx] = f2bf(scale * ldf(in, (size_t)(k0 + ty + i * 8) * N + (n0 + tx), isbf));
    __syncthreads();
    #pragma unroll
    for (int i = 0; i < 4; i++)
        out[(size_t)(n0 + ty + i * 8) * K + (k0 + tx)] = tile[tx][ty + i * 8];
}

// ---------------- fused q/k bias vector (q part pre-scaled) ----------------
__global__ void prep_bias_kernel(const void* __restrict__ bq, const void* __restrict__ bk,
                                 const int* __restrict__ flagp, float* __restrict__ bqk)
{
    int isbf = *flagp;
    int t = blockIdx.x * 256 + threadIdx.x;
    if (t < 512)       bqk[t] = 0.125f * ldf(bq, t, isbf);
    else if (t < 1024) bqk[t] = ldf(bk, t - 512, isbf);
}

// ---------------- per-window voxel selection (stable order, cap 256) ----------------
__global__ void voxsel_kernel(const int* __restrict__ vy, const int* __restrict__ vx,
                              int* __restrict__ sel)
{
    int n = blockIdx.x;                 // 64 windows, 64 threads (1 wave)
    int lane = threadIdx.x;
    int y0 = (n >> 3) << 3, x0 = (n & 7) << 3;
    int count = 0;
    for (int base = 0; base < NV_TOT; base += 64) {
        int v = base + lane;
        int yy = vy[v], xx = vx[v];
        bool m = (yy >= y0) && (yy < y0 + 16) && (xx >= x0) && (xx < x0 + 16);
        u64 mask = __ballot(m);
        int pos = count + __popcll(mask & ((1ull << lane) - 1ull));
        if (m && pos < VCAP) sel[n * VCAP + pos] = v;
        count += __popcll(mask);
    }
    for (int j = lane; j < VCAP; j += 64)
        if (j >= count) sel[n * VCAP + j] = -1;
}

// ---------------- gather tokens + LN1 -> h (bf16), validity flags ----------------
__global__ __launch_bounds__(256) void ln1_kernel(
    const void* __restrict__ patch, const void* __restrict__ vox,
    const void* __restrict__ g, const void* __restrict__ b,
    const int* __restrict__ sel, const int* __restrict__ flagp,
    u16* __restrict__ h, unsigned char* __restrict__ validk)
{
    int isbf = *flagp;
    int r = blockIdx.x * 4 + (threadIdx.x >> 6);    // one wave per row
    int lane = threadIdx.x & 63;
    int n = r >> 9, s = r & 511;
    const void* tok = nullptr;
    size_t base = 0;
    bool valid;
    if (s < A_TOK) {
        int wy = s >> 4, wx = s & 15;
        int iy = ((n >> 3) << 3) + wy, ix = ((n & 7) << 3) + wx;
        valid = (iy < P_DIM) && (ix < P_DIM);
        tok = patch; base = (size_t)(iy * P_DIM + ix) * C_DIM;
    } else {
        int idx = sel[n * VCAP + (s - A_TOK)];
        valid = (idx >= 0);
        tok = vox; base = valid ? (size_t)idx * C_DIM : 0;
    }
    float4 xa = make_float4(0.f, 0.f, 0.f, 0.f), xb = xa;
    if (valid) {
        xa = ld4(tok, base + lane * 4, isbf);
        xb = ld4(tok, base + 256 + lane * 4, isbf);
    }
    float sum = xa.x + xa.y + xa.z + xa.w + xb.x + xb.y + xb.z + xb.w;
    float sq  = xa.x * xa.x + xa.y * xa.y + xa.z * xa.z + xa.w * xa.w
              + xb.x * xb.x + xb.y * xb.y + xb.z * xb.z + xb.w * xb.w;
    #pragma unroll
    for (int off = 32; off; off >>= 1) {
        sum += __shfl_xor(sum, off, 64);
        sq  += __shfl_xor(sq,  off, 64);
    }
    float mean = sum * (1.f / C_DIM);
    float var  = fmaxf(sq * (1.f / C_DIM) - mean * mean, 0.f);
    float rstd = rsqrtf(var + 1e-5f);
    float4 ga = ld4(g, lane * 4, isbf);
    float4 gb = ld4(g, 256 + lane * 4, isbf);
    float4 ba = ld4(b, lane * 4, isbf);
    float4 bb = ld4(b, 256 + lane * 4, isbf);
    ushort4 oa, ob;
    oa.x = f2bf((xa.x - mean) * rstd * ga.x + ba.x);
    oa.y = f2bf((xa.y - mean) * rstd * ga.y + ba.y);
    oa.z = f2bf((xa.z - mean) * rstd * ga.z + ba.z);
    oa.w = f2bf((xa.w - mean) * rstd * ga.w + ba.w);
    ob.x = f2bf((xb.x - mean) * rstd * gb.x + bb.x);
    ob.y = f2bf((xb.y - mean) * rstd * gb.y + bb.y);
    ob.z = f2bf((xb.z - mean) * rstd * gb.z + bb.z);
    ob.w = f2bf((xb.w - mean) * rstd * gb.w + bb.w);
    ((ushort4*)(h + (size_t)r * C_DIM))[lane]      = oa;
    ((ushort4*)(h + (size_t)r * C_DIM))[lane + 64] = ob;
    if (lane == 0) validk[r] = valid ? 1 : 0;
}

// ---------------- LN2 over f32 rows -> bf16 ----------------
__global__ __launch_bounds__(256) void ln2_kernel(
    const float* __restrict__ x,
    const void* __restrict__ g, const void* __restrict__ b,
    const int* __restrict__ flagp,
    u16* __restrict__ h2)
{
    int isbf = *flagp;
    int r = blockIdx.x * 4 + (threadIdx.x >> 6);
    int lane = threadIdx.x & 63;
    const float* src = x + (size_t)r * C_DIM;
    float4 xa = ((const float4*)src)[lane];
    float4 xb = ((const float4*)src)[lane + 64];
    float sum = xa.x + xa.y + xa.z + xa.w + xb.x + xb.y + xb.z + xb.w;
    float sq  = xa.x * xa.x + xa.y * xa.y + xa.z * xa.z + xa.w * xa.w
              + xb.x * xb.x + xb.y * xb.y + xb.z * xb.z + xb.w * xb.w;
    #pragma unroll
    for (int off = 32; off; off >>= 1) {
        sum += __shfl_xor(sum, off, 64);
        sq  += __shfl_xor(sq,  off, 64);
    }
    float mean = sum * (1.f / C_DIM);
    float var  = fmaxf(sq * (1.f / C_DIM) - mean * mean, 0.f);
    float rstd = rsqrtf(var + 1e-5f);
    float4 ga = ld4(g, lane * 4, isbf);
    float4 gb = ld4(g, 256 + lane * 4, isbf);
    float4 ba = ld4(b, lane * 4, isbf);
    float4 bb = ld4(b, 256 + lane * 4, isbf);
    ushort4 oa, ob;
    oa.x = f2bf((xa.x - mean) * rstd * ga.x + ba.x);
    oa.y = f2bf((xa.y - mean) * rstd * ga.y + ba.y);
    oa.z = f2bf((xa.z - mean) * rstd * ga.z + ba.z);
    oa.w = f2bf((xa.w - mean) * rstd * ga.w + ba.w);
    ob.x = f2bf((xb.x - mean) * rstd * gb.x + bb.x);
    ob.y = f2bf((xb.y - mean) * rstd * gb.y + bb.y);
    ob.z = f2bf((xb.z - mean) * rstd * gb.z + bb.z);
    ob.w = f2bf((xb.w - mean) * rstd * gb.w + bb.w);
    ((ushort4*)(h2 + (size_t)r * C_DIM))[lane]      = oa;
    ((ushort4*)(h2 + (size_t)r * C_DIM))[lane + 64] = ob;
}

// ---------------- generic bf16 MFMA GEMM: C = op(A @ B^T + bias) ----------------
#define GF_GELU      2
#define GF_OUT_F32   4
#define GF_RES_F32   8    // += res (f32, [M][N])
#define GF_RES_PATCH 16   // += gathered patch token (raw dtype), valid positions only
#define GF_QK        32   // split store: cols<512 -> Cout (q, compact patch rows), else Cout2 (k)
#define GF_BIAS_ROW  64   // bias indexed by output row (for V^T gemm)
#define GF_BIAS_F32  128  // bias is prepped f32 array

__global__ __launch_bounds__(256) void gemm_kernel(
    const u16* __restrict__ A, const u16* __restrict__ BT,
    const void* __restrict__ bias,
    void* __restrict__ Cout, void* __restrict__ Cout2, const void* __restrict__ resv,
    const int* __restrict__ flagp,
    int M, int N, int K, int flags, int ldc)
{
    __shared__ u16 smem[2 * 128 * 64];   // As = smem, Bs = smem+8192 (u16); epilogue stage reuse
    int tid = threadIdx.x;
    int m0 = blockIdx.y * 128, n0 = blockIdx.x * 128;
    if ((flags & GF_QK) && n0 < 512 && (m0 & 511) >= 256) return;  // voxel rows need no Q
    int isbf = *flagp;
    int w = tid >> 6, lane = tid & 63;
    int wr = (w >> 1) * 64, wc = (w & 1) * 64;
    int l16 = lane & 15, quad = lane >> 4;
    u16* As = smem;
    u16* Bs = smem + 8192;

    f32x4 acc[4][4];
    #pragma unroll
    for (int i = 0; i < 4; i++)
        #pragma unroll
        for (int j = 0; j < 4; j++) { acc[i][j][0] = 0.f; acc[i][j][1] = 0.f; acc[i][j][2] = 0.f; acc[i][j][3] = 0.f; }

    int swz = (l16 & 7);                   // frag-read chunk swizzle key
    for (int k0 = 0; k0 < K; k0 += 64) {
        #pragma unroll
        for (int it = 0; it < 4; it++) {
            int c = (it * 4 + w) * 64 + lane;   // 0..1023 chunk slots
            int row = c >> 3, phys = c & 7;
            int kc = phys ^ (row & 7);          // XOR swizzle: break 128B-stride bank aliasing
            gload16(A  + (size_t)(m0 + row) * K + k0 + kc * 8, As + (size_t)c * 8);
            gload16(BT + (size_t)(n0 + row) * K + k0 + kc * 8, Bs + (size_t)c * 8);
        }
        __syncthreads();
        #pragma unroll
        for (int ks = 0; ks < 2; ks++) {
            bf16x8 a[4], b[4];
            #pragma unroll
            for (int i = 0; i < 4; i++) {
                int chunk = (ks * 4 + quad) ^ swz;
                a[i] = *(const bf16x8*)&As[(wr + i * 16 + l16) * 64 + chunk * 8];
            }
            #pragma unroll
            for (int j = 0; j < 4; j++) {
                int chunk = (ks * 4 + quad) ^ swz;
                b[j] = *(const bf16x8*)&Bs[(wc + j * 16 + l16) * 64 + chunk * 8];
            }
            #pragma unroll
            for (int i = 0; i < 4; i++)
                #pragma unroll
                for (int j = 0; j < 4; j++)
                    acc[i][j] = __builtin_amdgcn_mfma_f32_16x16x32_bf16(a[i], b[j], acc[i][j], 0, 0, 0);
        }
        __syncthreads();
    }

    // ---------- epilogue ----------
    u16* st = smem + w * 4096;          // per-wave 64x64 bf16 stage (reuses tile LDS)
    #pragma unroll
    for (int i = 0; i < 4; i++) {
        #pragma unroll
        for (int j = 0; j < 4; j++) {
            int gcol = n0 + wc + j * 16 + l16;
            float bc = 0.f;
            if (!(flags & GF_BIAS_ROW)) {
                if (flags & GF_BIAS_F32) bc = ((const float*)bias)[gcol];
                else if (bias)           bc = ldf(bias, gcol, isbf);
            }
            #pragma unroll
            for (int r2 = 0; r2 < 4; r2++) {
                int lrow = wr + i * 16 + quad * 4 + r2;
                int grow = m0 + lrow;
                float v = acc[i][j][r2] + ((flags & GF_BIAS_ROW) ? ldf(bias, grow, isbf) : bc);
                if (flags & GF_GELU) v = 0.5f * v * (1.f + erff(v * 0.70710678118654752f));
                if (flags & GF_RES_F32) v += ((const float*)resv)[(size_t)grow * N + gcol];
                if (flags & GF_RES_PATCH) {
                    int nn = grow >> 8, s = grow & 255;
                    int iy = ((nn >> 3) << 3) + (s >> 4);
                    int ix = ((nn & 7) << 3) + (s & 15);
                    if (iy < P_DIM && ix < P_DIM)
                        v += ldf(resv, (size_t)(iy * P_DIM + ix) * C_DIM + gcol, isbf);
                }
                if (flags & GF_OUT_F32)
                    ((float*)Cout)[(size_t)grow * ldc + gcol] = v;
                else
                    st[(i * 16 + quad * 4 + r2) * 64 + j * 16 + l16] = f2bf(v);
            }
        }
    }
    if (!(flags & GF_OUT_F32)) {
        asm volatile("" ::: "memory");   // same-wave LDS: block reorder, no barrier needed
        u16* cdst; int cst;
        if (flags & GF_QK) {
            cst = 512;
            if (n0 < 512)
                cdst = (u16*)Cout  + (size_t)(((m0 >> 9) << 8) + (m0 & 255) + wr) * 512 + (n0 + wc);
            else
                cdst = (u16*)Cout2 + (size_t)(m0 + wr) * 512 + (n0 - 512 + wc);
        } else {
            cst = ldc;
            cdst = (u16*)Cout + (size_t)(m0 + wr) * ldc + (n0 + wc);
        }
        #pragma unroll
        for (int rr = 0; rr < 8; rr++) {
            int row = rr * 8 + (lane >> 3);
            uint4 val = *(const uint4*)&st[row * 64 + (lane & 7) * 8];
            *(uint4*)(cdst + (size_t)row * cst + (lane & 7) * 8) = val;   // 128B/row coalesced
        }
    }
}

// ---------------- flash attention per (window, head); patch queries only ----------------
// exp(s) without max-shift (scores bounded: scale folded into q, unit-variance inputs);
// K and V^T tiles staged via async DMA with XOR chunk swizzle; O staged via LDS for
// coalesced 128B stores.
__global__ __launch_bounds__(256) void attn_kernel(
    const u16* __restrict__ q, const u16* __restrict__ k, const u16* __restrict__ vtg,
    const unsigned char* __restrict__ validk,
    u16* __restrict__ o)
{
    __shared__ u16 sK[64 * 64];          // [key][d], DMA-staged, swizzled chunks
    __shared__ u16 sV[64 * 64];          // [d][key], DMA-staged from V^T, swizzled chunks
    __shared__ u16 sP[4 * 64 * 68];      // per-wave P tile (padded)
    int h = blockIdx.x, n = blockIdx.y;
    int tid = threadIdx.x;
    int w = tid >> 6, lane = tid & 63;
    int l16 = lane & 15, quad = lane >> 4;
    int swz = (l16 & 7);

    bf16x8 qf[4][2];
    #pragma unroll
    for (int i = 0; i < 4; i++)
        #pragma unroll
        for (int ks = 0; ks < 2; ks++) {
            int row = n * A_TOK + w * 64 + i * 16 + l16;       // compact q
            int col = h * HDIM + ks * 32 + quad * 8;
            qf[i][ks] = *(const bf16x8*)(q + (size_t)row * C_DIM + col);
        }

    f32x4 oacc[4][4];
    float lsum[4][4];
    #pragma unroll
    for (int i = 0; i < 4; i++)
        #pragma unroll
        for (int j = 0; j < 4; j++) {
            oacc[i][j][0] = 0.f; oacc[i][j][1] = 0.f; oacc[i][j][2] = 0.f; oacc[i][j][3] = 0.f;
            lsum[i][j] = 0.f;
        }

    for (int ktile = 0; ktile < 8; ktile++) {
        __syncthreads();                       // prior tile's readers done before overwrite
        #pragma unroll
        for (int it = 0; it < 2; it++) {
            int c = it * 256 + w * 64 + lane;  // 0..511 chunk slots
            int row = c >> 3, phys = c & 7;
            int kc = phys ^ (row & 7);
            int grow = n * S_TOK + ktile * 64 + row;
            gload16(k + (size_t)grow * C_DIM + h * HDIM + kc * 8, sK + (size_t)c * 8);
            gload16(vtg + (size_t)(h * HDIM + row) * (size_t)NROW + n * S_TOK + ktile * 64 + kc * 8,
                    sV + (size_t)c * 8);
        }
        __syncthreads();

        f32x4 sacc[4][4];
        #pragma unroll
        for (int i = 0; i < 4; i++)
            #pragma unroll
            for (int j = 0; j < 4; j++) { sacc[i][j][0] = 0.f; sacc[i][j][1] = 0.f; sacc[i][j][2] = 0.f; sacc[i][j][3] = 0.f; }
        #pragma unroll
        for (int ks = 0; ks < 2; ks++) {
            int chunk = (ks * 4 + quad) ^ swz;
            bf16x8 bfr[4];
            #pragma unroll
            for (int j = 0; j < 4; j++) bfr[j] = *(const bf16x8*)&sK[(j * 16 + l16) * 64 + chunk * 8];
            #pragma unroll
            for (int i = 0; i < 4; i++)
                #pragma unroll
                for (int j = 0; j < 4; j++)
                    sacc[i][j] = __builtin_amdgcn_mfma_f32_16x16x32_bf16(qf[i][ks], bfr[j], sacc[i][j], 0, 0, 0);
        }

        bool kvalid[4];
        #pragma unroll
        for (int j = 0; j < 4; j++)
            kvalid[j] = validk[n * S_TOK + ktile * 64 + j * 16 + l16] != 0;

        #pragma unroll
        for (int i = 0; i < 4; i++)
            #pragma unroll
            for (int r2 = 0; r2 < 4; r2++) {
                int prow = i * 16 + quad * 4 + r2;
                #pragma unroll
                for (int j = 0; j < 4; j++) {
                    float p = kvalid[j] ? __expf(sacc[i][j][r2]) : 0.f;
                    lsum[i][r2] += p;
                    sP[(w * 64 + prow) * 68 + j * 16 + l16] = f2bf(p);
                }
            }
        asm volatile("" ::: "memory");   // per-wave LDS: forbid read-before-write reorder
        #pragma unroll
        for (int ks = 0; ks < 2; ks++) {
            int chunk = (ks * 4 + quad) ^ swz;
            bf16x8 pa[4], vb[4];
            #pragma unroll
            for (int i = 0; i < 4; i++)   pa[i]  = *(const bf16x8*)&sP[(w * 64 + i * 16 + l16) * 68 + ks * 32 + quad * 8];
            #pragma unroll
            for (int jd = 0; jd < 4; jd++) vb[jd] = *(const bf16x8*)&sV[(jd * 16 + l16) * 64 + chunk * 8];
            #pragma unroll
            for (int i = 0; i < 4; i++)
                #pragma unroll
                for (int jd = 0; jd < 4; jd++)
                    oacc[i][jd] = __builtin_amdgcn_mfma_f32_16x16x32_bf16(pa[i], vb[jd], oacc[i][jd], 0, 0, 0);
        }
    }

    // normalize, stage O per-wave in LDS, coalesced 128B stores
    asm volatile("" ::: "memory");
    u16* ost = sP + w * (64 * 68);       // flat 64x64 region, stride 64
    #pragma unroll
    for (int i = 0; i < 4; i++) {
        #pragma unroll
        for (int r2 = 0; r2 < 4; r2++) {
            float l = lsum[i][r2];
            #pragma unroll
            for (int off = 8; off; off >>= 1)
                l += __shfl_xor(l, off, 64);
            float inv = (l > 0.f) ? 1.f / l : 0.f;
            #pragma unroll
            for (int jd = 0; jd < 4; jd++)
                ost[(i * 16 + quad * 4 + r2) * 64 + jd * 16 + l16] = f2bf(oacc[i][jd][r2] * inv);
        }
    }
    asm volatile("" ::: "memory");
    u16* obase = o + (size_t)(n * A_TOK + w * 64) * C_DIM + h * HDIM;
    #pragma unroll
    for (int rr = 0; rr < 8; rr++) {
        int row = rr * 8 + (lane >> 3);
        uint4 val = *(const uint4*)&ost[row * 64 + (lane & 7) * 8];
        *(uint4*)(obase + (size_t)row * C_DIM + (lane & 7) * 8) = val;
    }
}

// ---------------- final gather-average (replaces scatter/atomics) ----------------
__global__ __launch_bounds__(256) void gather_kernel(const float* __restrict__ xf,
                                                     void* __restrict__ out,
                                                     const int* __restrict__ flagp)
{
    int isbf = *flagp;
    int gid = blockIdx.x * 256 + threadIdx.x;    // pixel*128 + float4-chunk
    int p = gid >> 7, cv = gid & 127;
    int py = p >> 6, px = p & 63;
    float4 acc = make_float4(0.f, 0.f, 0.f, 0.f);
    int cnt = 0;
    #pragma unroll
    for (int dy = 0; dy < 2; dy++) {
        int y0 = ((py >> 3) - dy) << 3;
        if (y0 < 0) continue;
        #pragma unroll
        for (int dx = 0; dx < 2; dx++) {
            int x0 = ((px >> 3) - dx) << 3;
            if (x0 < 0) continue;
            int n = ((y0 >> 3) << 3) + (x0 >> 3);
            int s = (py - y0) * 16 + (px - x0);
            float4 t = ((const float4*)(xf + (size_t)(n * A_TOK + s) * C_DIM))[cv];
            acc.x += t.x; acc.y += t.y; acc.z += t.z; acc.w += t.w;
            cnt++;
        }
    }
    float inv = 1.f / (float)cnt;
    acc.x *= inv; acc.y *= inv; acc.z *= inv; acc.w *= inv;
    if (isbf) {
        ushort4 o;
        o.x = f2bf(acc.x); o.y = f2bf(acc.y); o.z = f2bf(acc.z); o.w = f2bf(acc.w);
        ((ushort4*)out)[gid] = o;
    } else {
        ((float4*)out)[gid] = acc;
    }
}

extern "C" void kernel_launch(void* const* d_in, const int* in_sizes, int n_in,
                              void* d_out, int out_size, void* d_ws, size_t ws_size,
                              hipStream_t stream)
{
    const void* patch = d_in[0];
    const void* vox   = d_in[1];
    const void* ln1g  = d_in[2];
    const void* ln1b  = d_in[3];
    const void* wq = d_in[4];  const void* bq = d_in[5];
    const void* wk = d_in[6];  const void* bk = d_in[7];
    const void* wv = d_in[8];  const void* bv = d_in[9];
    const void* wo = d_in[10]; const void* bo = d_in[11];
    const void* ln2g = d_in[12];
    const void* ln2b = d_in[13];
    const void* w1 = d_in[14]; const void* b1 = d_in[15];
    const void* w2 = d_in[16]; const void* b2 = d_in[17];
    const int* vpy = (const int*)d_in[18];
    const int* vpx = (const int*)d_in[19];

    const size_t MB = 1ull << 20;
    char* ws = (char*)d_ws;
    if (ws_size < 183 * MB) return;   // insufficient workspace -> visible failure

    u16*  hbuf  = (u16*)(ws + 0);          // [32768][512] bf16, 32MB
    u16*  kbuf  = (u16*)(ws + 32 * MB);    // [32768][512] bf16, 32MB
    u16*  vtt   = (u16*)(ws + 64 * MB);    // V^T [512][32768] bf16, 32MB
    u16*  qbuf  = (u16*)(ws + 96 * MB);    // [16384][512] bf16, 16MB (compact patch)
    u16*  obuf  = (u16*)(ws + 112 * MB);   // 16MB
    float* xbuf = (float*)(ws + 128 * MB); // [16384][512] f32, 32MB
    u16*  h2buf = (u16*)(ws + 160 * MB);   // 16MB
    u16*  tbuf  = (u16*)(ws + 0);          // [16384][2048] bf16, 64MB (reuse h+k, dead)
    float* xfbuf = (float*)(ws + 64 * MB); // 32MB (reuse vtt, dead after attn)
    u16* wqkT = (u16*)(ws + 176 * MB);     // [1024][512] bf16, 1MB (q rows pre-scaled)
    u16* wvT  = (u16*)(ws + 177 * MB);     // 0.5MB
    u16* woT  = (u16*)(ws + 177 * MB + 512 * 1024);
    u16* w1T  = (u16*)(ws + 178 * MB);     // [2048][512], 2MB
    u16* w2T  = (u16*)(ws + 180 * MB);     // [512][2048], 2MB
    int* sel = (int*)(ws + 182 * MB);      // 64KB
    unsigned char* validk = (unsigned char*)(ws + 182 * MB + 64 * 1024); // 32KB
    int* flagp = (int*)(ws + 182 * MB + 128 * 1024);
    float* bqk = (float*)(ws + 182 * MB + 132 * 1024);  // [1024] f32

    detect_kernel<<<1, 256, 0, stream>>>((const u32*)patch, flagp);

    dim3 blkT(32, 8);
    wtrans_kernel<<<dim3(16, 16), blkT, 0, stream>>>(wq, wqkT,             512, 512,  flagp, 0.125f);
    wtrans_kernel<<<dim3(16, 16), blkT, 0, stream>>>(wk, wqkT + 512 * 512, 512, 512,  flagp, 1.f);
    wtrans_kernel<<<dim3(16, 16), blkT, 0, stream>>>(wv, wvT,              512, 512,  flagp, 1.f);
    wtrans_kernel<<<dim3(16, 16), blkT, 0, stream>>>(wo, woT,              512, 512,  flagp, 1.f);
    wtrans_kernel<<<dim3(64, 16), blkT, 0, stream>>>(w1, w1T,              512, 2048, flagp, 1.f);
    wtrans_kernel<<<dim3(16, 64), blkT, 0, stream>>>(w2, w2T,              2048, 512, flagp, 1.f);
    prep_bias_kernel<<<4, 256, 0, stream>>>(bq, bk, flagp, bqk);

    voxsel_kernel<<<NWIN, 64, 0, stream>>>(vpy, vpx, sel);
    ln1_kernel<<<NROW / 4, 256, 0, stream>>>(patch, vox, ln1g, ln1b, sel, flagp, hbuf, validk);

    // fused QK gemm: N=1024 (cols 0-511 -> q compact/scaled, 512-1023 -> k)
    gemm_kernel<<<dim3(8, NROW / 128), 256, 0, stream>>>(hbuf, wqkT, bqk, qbuf, kbuf, nullptr,
        flagp, NROW, 1024, 512, GF_QK | GF_BIAS_F32, 512);
    // V^T = Wv^T * h^T : M=512 channels, N=32768 tokens, row bias
    gemm_kernel<<<dim3(NROW / 128, 4), 256, 0, stream>>>(wvT, hbuf, bv, vtt, nullptr, nullptr,
        flagp, 512, NROW, 512, GF_BIAS_ROW, NROW);

    attn_kernel<<<dim3(HEADS, NWIN), 256, 0, stream>>>(qbuf, kbuf, vtt, validk, obuf);

    // x = tokens(patch gather) + o @ wo + bo   (f32)
    gemm_kernel<<<dim3(4, NPATCH / 128), 256, 0, stream>>>(obuf, woT, bo, xbuf, nullptr, patch,
        flagp, NPATCH, 512, 512, GF_OUT_F32 | GF_RES_PATCH, 512);

    ln2_kernel<<<NPATCH / 4, 256, 0, stream>>>(xbuf, ln2g, ln2b, flagp, h2buf);

    gemm_kernel<<<dim3(16, NPATCH / 128), 256, 0, stream>>>(h2buf, w1T, b1, tbuf, nullptr, nullptr,
        flagp, NPATCH, 2048, 512, GF_GELU, 2048);
    gemm_kernel<<<dim3(4, NPATCH / 128), 256, 0, stream>>>(tbuf, w2T, b2, xfbuf, nullptr, xbuf,
        flagp, NPATCH, 512, 2048, GF_OUT_F32 | GF_RES_F32, 512);

    gather_kernel<<<(4096 * 128) / 256, 256, 0, stream>>>(xfbuf, d_out, flagp);
}

// Round 5
// 512.393 us; speedup vs baseline: 1.1891x; 1.0632x over previous
//
#include <hip/hip_runtime.h>
#include <math.h>

using u16 = unsigned short;
using u32 = unsigned int;
using u64 = unsigned long long;
using bf16x8 = __attribute__((ext_vector_type(8))) short;
using f32x4  = __attribute__((ext_vector_type(4))) float;

#define C_DIM   512
#define HEADS   8
#define HDIM    64
#define P_DIM   64
#define A_TOK   256
#define VCAP    256
#define S_TOK   512
#define NWIN    64
#define NROW    32768      // NWIN * S_TOK
#define NPATCH  16384      // NWIN * A_TOK
#define MLP_DIM 2048
#define NV_TOT  2048

__device__ __forceinline__ float bf2f(u16 b) { return __uint_as_float(((u32)b) << 16); }
__device__ __forceinline__ u16 f2bf(float f) {
    u32 u = __float_as_uint(f);
    return (u16)((u + 0x7fffu + ((u >> 16) & 1u)) >> 16);   // RNE
}
__device__ __forceinline__ float4 bf4f(ushort4 v) {
    return make_float4(bf2f(v.x), bf2f(v.y), bf2f(v.z), bf2f(v.w));
}
// dtype-agnostic loads from RAW inputs: isbf=1 -> bf16, else f32
__device__ __forceinline__ float ldf(const void* p, size_t e, int isbf) {
    return isbf ? bf2f(((const u16*)p)[e]) : ((const float*)p)[e];
}
__device__ __forceinline__ float4 ld4(const void* p, size_t e, int isbf) {  // e % 4 == 0
    if (isbf) return bf4f(*(const ushort4*)((const u16*)p + e));
    return *(const float4*)((const float*)p + e);
}
// async global->LDS, 16B per lane; lds dest must be wave-uniform-base + lane*16
__device__ __forceinline__ void gload16(const u16* g, u16* l) {
    __builtin_amdgcn_global_load_lds(
        (const __attribute__((address_space(1))) u32*)g,
        (__attribute__((address_space(3))) u32*)l, 16, 0, 0);
}
// tanh-form GELU via sigmoid: x*sigmoid(1.5957691x + 0.0713548x^3); |err| <= ~3e-4
__device__ __forceinline__ float fast_gelu(float x) {
    float x2 = x * x;
    float z = x * (-1.5957691216f - 0.07135481283f * x2);
    return x / (1.f + __expf(z));
}

// ---------------- dtype detector: vote on low-16-bits-as-bf16 plausibility ----------------
__global__ void detect_kernel(const u32* __restrict__ patch, int* __restrict__ flag)
{
    __shared__ int sm[256];
    int t = threadIdx.x;
    int cnt = 0;
    for (int i = t; i < 4096; i += 256) {
        u32 w = patch[i];
        float v = __uint_as_float((w & 0xffffu) << 16);
        float a = fabsf(v);
        if (a > 1e-8f && a < 1e4f) cnt++;
    }
    sm[t] = cnt;
    __syncthreads();
    for (int o = 128; o; o >>= 1) { if (t < o) sm[t] += sm[t + o]; __syncthreads(); }
    if (t == 0) *flag = (sm[0] > 2458) ? 1 : 0;    // >60% plausible => bf16 world
}

// ---------------- weight transpose: in [K][N] -> out [N][K] bf16, optional scale ------------
__global__ void wtrans_kernel(const void* __restrict__ in, u16* __restrict__ out,
                              int K, int N, const int* __restrict__ flagp, float scale)
{
    __shared__ u16 tile[32][33];
    int isbf = *flagp;
    int n0 = blockIdx.x * 32, k0 = blockIdx.y * 32;
    int tx = threadIdx.x, ty = threadIdx.y;   // block (32, 8)
    #pragma unroll
    for (int i = 0; i < 4; i++)
        tile[ty + i * 8][tx] = f2bf(scale * ldf(in, (size_t)(k0 + ty + i * 8) * N + (n0 + tx), isbf));
    __syncthreads();
    #pragma unroll
    for (int i = 0; i < 4; i++)
        out[(size_t)(n0 + ty + i * 8) * K + (k0 + tx)] = tile[tx][ty + i * 8];
}

// ---------------- fused q/k/v bias vector (q part pre-scaled), f32 ----------------
__global__ void prep_bias_kernel(const void* __restrict__ bq, const void* __restrict__ bk,
                                 const void* __restrict__ bv,
                                 const int* __restrict__ flagp, float* __restrict__ bqkv)
{
    int isbf = *flagp;
    int t = blockIdx.x * 256 + threadIdx.x;
    if (t < 512)       bqkv[t] = 0.125f * ldf(bq, t, isbf);
    else if (t < 1024) bqkv[t] = ldf(bk, t - 512, isbf);
    else if (t < 1536) bqkv[t] = ldf(bv, t - 1024, isbf);
}

// ---------------- per-window voxel selection (stable order, cap 256) ----------------
__global__ void voxsel_kernel(const int* __restrict__ vy, const int* __restrict__ vx,
                              int* __restrict__ sel)
{
    int n = blockIdx.x;                 // 64 windows, 64 threads (1 wave)
    int lane = threadIdx.x;
    int y0 = (n >> 3) << 3, x0 = (n & 7) << 3;
    int count = 0;
    for (int base = 0; base < NV_TOT; base += 64) {
        int v = base + lane;
        int yy = vy[v], xx = vx[v];
        bool m = (yy >= y0) && (yy < y0 + 16) && (xx >= x0) && (xx < x0 + 16);
        u64 mask = __ballot(m);
        int pos = count + __popcll(mask & ((1ull << lane) - 1ull));
        if (m && pos < VCAP) sel[n * VCAP + pos] = v;
        count += __popcll(mask);
    }
    for (int j = lane; j < VCAP; j += 64)
        if (j >= count) sel[n * VCAP + j] = -1;
}

// ---------------- gather tokens + LN1 -> h (bf16), validity flags ----------------
__global__ __launch_bounds__(256) void ln1_kernel(
    const void* __restrict__ patch, const void* __restrict__ vox,
    const void* __restrict__ g, const void* __restrict__ b,
    const int* __restrict__ sel, const int* __restrict__ flagp,
    u16* __restrict__ h, unsigned char* __restrict__ validk)
{
    int isbf = *flagp;
    int r = blockIdx.x * 4 + (threadIdx.x >> 6);    // one wave per row
    int lane = threadIdx.x & 63;
    int n = r >> 9, s = r & 511;
    const void* tok = nullptr;
    size_t base = 0;
    bool valid;
    if (s < A_TOK) {
        int wy = s >> 4, wx = s & 15;
        int iy = ((n >> 3) << 3) + wy, ix = ((n & 7) << 3) + wx;
        valid = (iy < P_DIM) && (ix < P_DIM);
        tok = patch; base = (size_t)(iy * P_DIM + ix) * C_DIM;
    } else {
        int idx = sel[n * VCAP + (s - A_TOK)];
        valid = (idx >= 0);
        tok = vox; base = valid ? (size_t)idx * C_DIM : 0;
    }
    float4 xa = make_float4(0.f, 0.f, 0.f, 0.f), xb = xa;
    if (valid) {
        xa = ld4(tok, base + lane * 4, isbf);
        xb = ld4(tok, base + 256 + lane * 4, isbf);
    }
    float sum = xa.x + xa.y + xa.z + xa.w + xb.x + xb.y + xb.z + xb.w;
    float sq  = xa.x * xa.x + xa.y * xa.y + xa.z * xa.z + xa.w * xa.w
              + xb.x * xb.x + xb.y * xb.y + xb.z * xb.z + xb.w * xb.w;
    #pragma unroll
    for (int off = 32; off; off >>= 1) {
        sum += __shfl_xor(sum, off, 64);
        sq  += __shfl_xor(sq,  off, 64);
    }
    float mean = sum * (1.f / C_DIM);
    float var  = fmaxf(sq * (1.f / C_DIM) - mean * mean, 0.f);
    float rstd = rsqrtf(var + 1e-5f);
    float4 ga = ld4(g, lane * 4, isbf);
    float4 gb = ld4(g, 256 + lane * 4, isbf);
    float4 ba = ld4(b, lane * 4, isbf);
    float4 bb = ld4(b, 256 + lane * 4, isbf);
    ushort4 oa, ob;
    oa.x = f2bf((xa.x - mean) * rstd * ga.x + ba.x);
    oa.y = f2bf((xa.y - mean) * rstd * ga.y + ba.y);
    oa.z = f2bf((xa.z - mean) * rstd * ga.z + ba.z);
    oa.w = f2bf((xa.w - mean) * rstd * ga.w + ba.w);
    ob.x = f2bf((xb.x - mean) * rstd * gb.x + bb.x);
    ob.y = f2bf((xb.y - mean) * rstd * gb.y + bb.y);
    ob.z = f2bf((xb.z - mean) * rstd * gb.z + bb.z);
    ob.w = f2bf((xb.w - mean) * rstd * gb.w + bb.w);
    ((ushort4*)(h + (size_t)r * C_DIM))[lane]      = oa;
    ((ushort4*)(h + (size_t)r * C_DIM))[lane + 64] = ob;
    if (lane == 0) validk[r] = valid ? 1 : 0;
}

// ---------------- LN2 over f32 rows -> bf16 ----------------
__global__ __launch_bounds__(256) void ln2_kernel(
    const float* __restrict__ x,
    const void* __restrict__ g, const void* __restrict__ b,
    const int* __restrict__ flagp,
    u16* __restrict__ h2)
{
    int isbf = *flagp;
    int r = blockIdx.x * 4 + (threadIdx.x >> 6);
    int lane = threadIdx.x & 63;
    const float* src = x + (size_t)r * C_DIM;
    float4 xa = ((const float4*)src)[lane];
    float4 xb = ((const float4*)src)[lane + 64];
    float sum = xa.x + xa.y + xa.z + xa.w + xb.x + xb.y + xb.z + xb.w;
    float sq  = xa.x * xa.x + xa.y * xa.y + xa.z * xa.z + xa.w * xa.w
              + xb.x * xb.x + xb.y * xb.y + xb.z * xb.z + xb.w * xb.w;
    #pragma unroll
    for (int off = 32; off; off >>= 1) {
        sum += __shfl_xor(sum, off, 64);
        sq  += __shfl_xor(sq,  off, 64);
    }
    float mean = sum * (1.f / C_DIM);
    float var  = fmaxf(sq * (1.f / C_DIM) - mean * mean, 0.f);
    float rstd = rsqrtf(var + 1e-5f);
    float4 ga = ld4(g, lane * 4, isbf);
    float4 gb = ld4(g, 256 + lane * 4, isbf);
    float4 ba = ld4(b, lane * 4, isbf);
    float4 bb = ld4(b, 256 + lane * 4, isbf);
    ushort4 oa, ob;
    oa.x = f2bf((xa.x - mean) * rstd * ga.x + ba.x);
    oa.y = f2bf((xa.y - mean) * rstd * ga.y + ba.y);
    oa.z = f2bf((xa.z - mean) * rstd * ga.z + ba.z);
    oa.w = f2bf((xa.w - mean) * rstd * ga.w + ba.w);
    ob.x = f2bf((xb.x - mean) * rstd * gb.x + bb.x);
    ob.y = f2bf((xb.y - mean) * rstd * gb.y + bb.y);
    ob.z = f2bf((xb.z - mean) * rstd * gb.z + bb.z);
    ob.w = f2bf((xb.w - mean) * rstd * gb.w + bb.w);
    ((ushort4*)(h2 + (size_t)r * C_DIM))[lane]      = oa;
    ((ushort4*)(h2 + (size_t)r * C_DIM))[lane + 64] = ob;
}

// ---------------- generic bf16 MFMA GEMM: C = op(A @ B^T + bias) ----------------
#define GF_GELU      2
#define GF_OUT_F32   4
#define GF_RES_F32   8    // += res (f32, [M][N])
#define GF_RES_PATCH 16   // += gathered patch token (raw dtype), valid positions only
#define GF_QKV       32   // N=1536: cols 0-511 q (compact, patch rows), 512-1023 k, 1024-1535 v^T

__global__ __launch_bounds__(256) void gemm_kernel(
    const u16* __restrict__ A, const u16* __restrict__ BT,
    const void* __restrict__ bias,
    void* __restrict__ Cout, void* __restrict__ Cout2, void* __restrict__ Cout3,
    const void* __restrict__ resv,
    const int* __restrict__ flagp,
    int M, int N, int K, int flags, int ldc)
{
    __shared__ u16 smem[2 * 128 * 64];   // As = smem, Bs = smem+8192 (u16); epilogue stage reuse
    int tid = threadIdx.x;
    int m0 = blockIdx.y * 128, n0 = blockIdx.x * 128;
    int region = (flags & GF_QKV) ? (n0 >> 9) : 0;   // 0:q 1:k 2:v^T
    if ((flags & GF_QKV) && region == 0 && (m0 & 511) >= 256) return;  // voxel rows need no Q
    int isbf = *flagp;
    int w = tid >> 6, lane = tid & 63;
    int wr = (w >> 1) * 64, wc = (w & 1) * 64;
    int l16 = lane & 15, quad = lane >> 4;
    u16* As = smem;
    u16* Bs = smem + 8192;
    bool vtb = (flags & GF_QKV) && (region == 2);   // transposed-output block

    f32x4 acc[4][4];
    #pragma unroll
    for (int i = 0; i < 4; i++)
        #pragma unroll
        for (int j = 0; j < 4; j++) { acc[i][j][0] = 0.f; acc[i][j][1] = 0.f; acc[i][j][2] = 0.f; acc[i][j][3] = 0.f; }

    int swz = (l16 & 7);                   // frag-read chunk swizzle key
    const u16* Xs = vtb ? Bs : As;         // first operand rows -> D rows
    const u16* Ys = vtb ? As : Bs;
    for (int k0 = 0; k0 < K; k0 += 64) {
        #pragma unroll
        for (int it = 0; it < 4; it++) {
            int c = (it * 4 + w) * 64 + lane;   // 0..1023 chunk slots
            int row = c >> 3, phys = c & 7;
            int kc = phys ^ (row & 7);          // XOR swizzle: break 128B-stride bank aliasing
            gload16(A  + (size_t)(m0 + row) * K + k0 + kc * 8, As + (size_t)c * 8);
            gload16(BT + (size_t)(n0 + row) * K + k0 + kc * 8, Bs + (size_t)c * 8);
        }
        __syncthreads();
        #pragma unroll
        for (int ks = 0; ks < 2; ks++) {
            bf16x8 a[4], b[4];
            #pragma unroll
            for (int i = 0; i < 4; i++) {
                int chunk = (ks * 4 + quad) ^ swz;
                a[i] = *(const bf16x8*)&Xs[(wr + i * 16 + l16) * 64 + chunk * 8];
            }
            #pragma unroll
            for (int j = 0; j < 4; j++) {
                int chunk = (ks * 4 + quad) ^ swz;
                b[j] = *(const bf16x8*)&Ys[(wc + j * 16 + l16) * 64 + chunk * 8];
            }
            #pragma unroll
            for (int i = 0; i < 4; i++)
                #pragma unroll
                for (int j = 0; j < 4; j++)
                    acc[i][j] = __builtin_amdgcn_mfma_f32_16x16x32_bf16(a[i], b[j], acc[i][j], 0, 0, 0);
        }
        __syncthreads();
    }

    // ---------- epilogue ----------
    u16* st = smem + w * 4096;          // per-wave 64x64 bf16 stage (reuses tile LDS)
    #pragma unroll
    for (int i = 0; i < 4; i++) {
        #pragma unroll
        for (int j = 0; j < 4; j++) {
            int gcol = n0 + wc + j * 16 + l16;    // (QKV col space for regions 0/1)
            float bc = 0.f;
            if (flags & GF_QKV) { if (!vtb) bc = ((const float*)bias)[gcol]; }
            else if (bias) bc = ldf(bias, gcol, isbf);
            #pragma unroll
            for (int r2 = 0; r2 < 4; r2++) {
                int lrow = wr + i * 16 + quad * 4 + r2;
                int grow = m0 + lrow;
                if (vtb) bc = ((const float*)bias)[n0 + lrow];   // channel-indexed bias
                float v = acc[i][j][r2] + bc;
                if (flags & GF_GELU) v = fast_gelu(v);
                if (flags & GF_RES_F32) v += ((const float*)resv)[(size_t)grow * N + gcol];
                if (flags & GF_RES_PATCH) {
                    int nn = grow >> 8, s = grow & 255;
                    int iy = ((nn >> 3) << 3) + (s >> 4);
                    int ix = ((nn & 7) << 3) + (s & 15);
                    if (iy < P_DIM && ix < P_DIM)
                        v += ldf(resv, (size_t)(iy * P_DIM + ix) * C_DIM + gcol, isbf);
                }
                if (flags & GF_OUT_F32)
                    ((float*)Cout)[(size_t)grow * ldc + gcol] = v;
                else
                    st[(i * 16 + quad * 4 + r2) * 64 + j * 16 + l16] = f2bf(v);
            }
        }
    }
    if (!(flags & GF_OUT_F32)) {
        asm volatile("" ::: "memory");   // same-wave LDS: block reorder, no barrier needed
        u16* cdst; int cst;
        if (flags & GF_QKV) {
            if (region == 0) {          // q: compact patch rows, pre-scaled
                cst = 512;
                cdst = (u16*)Cout  + (size_t)(((m0 >> 9) << 8) + (m0 & 255) + wr) * 512 + (n0 + wc);
            } else if (region == 1) {   // k
                cst = 512;
                cdst = (u16*)Cout2 + (size_t)(m0 + wr) * 512 + (n0 - 512 + wc);
            } else {                    // v^T: rows = channels, cols = tokens
                cst = NROW;
                cdst = (u16*)Cout3 + (size_t)(n0 - 1024 + wr) * NROW + (m0 + wc);
            }
        } else {
            cst = ldc;
            cdst = (u16*)Cout + (size_t)(m0 + wr) * ldc + (n0 + wc);
        }
        #pragma unroll
        for (int rr = 0; rr < 8; rr++) {
            int row = rr * 8 + (lane >> 3);
            uint4 val = *(const uint4*)&st[row * 64 + (lane & 7) * 8];
            *(uint4*)(cdst + (size_t)row * cst + (lane & 7) * 8) = val;   // 128B/row coalesced
        }
    }
}

// ---------------- flash attention per (window, head); patch queries only ----------------
__global__ __launch_bounds__(256) void attn_kernel(
    const u16* __restrict__ q, const u16* __restrict__ k, const u16* __restrict__ vtg,
    const unsigned char* __restrict__ validk,
    u16* __restrict__ o)
{
    __shared__ u16 sK[64 * 64];          // [key][d], DMA-staged, swizzled chunks
    __shared__ u16 sV[64 * 64];          // [d][key], DMA-staged from V^T, swizzled chunks
    __shared__ u16 sP[4 * 64 * 72];      // per-wave P tile (stride 72: b128-aligned, <=2-way)
    int h = blockIdx.x, n = blockIdx.y;
    int tid = threadIdx.x;
    int w = tid >> 6, lane = tid & 63;
    int l16 = lane & 15, quad = lane >> 4;
    int swz = (l16 & 7);

    bf16x8 qf[4][2];
    #pragma unroll
    for (int i = 0; i < 4; i++)
        #pragma unroll
        for (int ks = 0; ks < 2; ks++) {
            int row = n * A_TOK + w * 64 + i * 16 + l16;       // compact q
            int col = h * HDIM + ks * 32 + quad * 8;
            qf[i][ks] = *(const bf16x8*)(q + (size_t)row * C_DIM + col);
        }

    f32x4 oacc[4][4];
    float lsum[4][4];
    #pragma unroll
    for (int i = 0; i < 4; i++)
        #pragma unroll
        for (int j = 0; j < 4; j++) {
            oacc[i][j][0] = 0.f; oacc[i][j][1] = 0.f; oacc[i][j][2] = 0.f; oacc[i][j][3] = 0.f;
            lsum[i][j] = 0.f;
        }

    for (int ktile = 0; ktile < 8; ktile++) {
        __syncthreads();                       // prior tile's readers done before overwrite
        #pragma unroll
        for (int it = 0; it < 2; it++) {
            int c = it * 256 + w * 64 + lane;  // 0..511 chunk slots
            int row = c >> 3, phys = c & 7;
            int kc = phys ^ (row & 7);
            int grow = n * S_TOK + ktile * 64 + row;
            gload16(k + (size_t)grow * C_DIM + h * HDIM + kc * 8, sK + (size_t)c * 8);
            gload16(vtg + (size_t)(h * HDIM + row) * (size_t)NROW + n * S_TOK + ktile * 64 + kc * 8,
                    sV + (size_t)c * 8);
        }
        __syncthreads();

        f32x4 sacc[4][4];
        #pragma unroll
        for (int i = 0; i < 4; i++)
            #pragma unroll
            for (int j = 0; j < 4; j++) { sacc[i][j][0] = 0.f; sacc[i][j][1] = 0.f; sacc[i][j][2] = 0.f; sacc[i][j][3] = 0.f; }
        #pragma unroll
        for (int ks = 0; ks < 2; ks++) {
            int chunk = (ks * 4 + quad) ^ swz;
            bf16x8 bfr[4];
            #pragma unroll
            for (int j = 0; j < 4; j++) bfr[j] = *(const bf16x8*)&sK[(j * 16 + l16) * 64 + chunk * 8];
            #pragma unroll
            for (int i = 0; i < 4; i++)
                #pragma unroll
                for (int j = 0; j < 4; j++)
                    sacc[i][j] = __builtin_amdgcn_mfma_f32_16x16x32_bf16(qf[i][ks], bfr[j], sacc[i][j], 0, 0, 0);
        }

        bool kvalid[4];
        #pragma unroll
        for (int j = 0; j < 4; j++)
            kvalid[j] = validk[n * S_TOK + ktile * 64 + j * 16 + l16] != 0;

        #pragma unroll
        for (int i = 0; i < 4; i++)
            #pragma unroll
            for (int r2 = 0; r2 < 4; r2++) {
                int prow = i * 16 + quad * 4 + r2;
                #pragma unroll
                for (int j = 0; j < 4; j++) {
                    float p = kvalid[j] ? __expf(sacc[i][j][r2]) : 0.f;
                    lsum[i][r2] += p;
                    sP[(w * 64 + prow) * 72 + j * 16 + l16] = f2bf(p);
                }
            }
        asm volatile("" ::: "memory");   // per-wave LDS: forbid read-before-write reorder
        #pragma unroll
        for (int ks = 0; ks < 2; ks++) {
            int chunk = (ks * 4 + quad) ^ swz;
            bf16x8 pa[4], vb[4];
            #pragma unroll
            for (int i = 0; i < 4; i++)   pa[i]  = *(const bf16x8*)&sP[(w * 64 + i * 16 + l16) * 72 + ks * 32 + quad * 8];
            #pragma unroll
            for (int jd = 0; jd < 4; jd++) vb[jd] = *(const bf16x8*)&sV[(jd * 16 + l16) * 64 + chunk * 8];
            #pragma unroll
            for (int i = 0; i < 4; i++)
                #pragma unroll
                for (int jd = 0; jd < 4; jd++)
                    oacc[i][jd] = __builtin_amdgcn_mfma_f32_16x16x32_bf16(pa[i], vb[jd], oacc[i][jd], 0, 0, 0);
        }
    }

    // normalize, stage O per-wave in LDS, coalesced 128B stores
    asm volatile("" ::: "memory");
    u16* ost = sP + w * (64 * 72);       // flat 64x64 region, stride 64
    #pragma unroll
    for (int i = 0; i < 4; i++) {
        #pragma unroll
        for (int r2 = 0; r2 < 4; r2++) {
            float l = lsum[i][r2];
            #pragma unroll
            for (int off = 8; off; off >>= 1)
                l += __shfl_xor(l, off, 64);
            float inv = (l > 0.f) ? 1.f / l : 0.f;
            #pragma unroll
            for (int jd = 0; jd < 4; jd++)
                ost[(i * 16 + quad * 4 + r2) * 64 + jd * 16 + l16] = f2bf(oacc[i][jd][r2] * inv);
        }
    }
    asm volatile("" ::: "memory");
    u16* obase = o + (size_t)(n * A_TOK + w * 64) * C_DIM + h * HDIM;
    #pragma unroll
    for (int rr = 0; rr < 8; rr++) {
        int row = rr * 8 + (lane >> 3);
        uint4 val = *(const uint4*)&ost[row * 64 + (lane & 7) * 8];
        *(uint4*)(obase + (size_t)row * C_DIM + (lane & 7) * 8) = val;
    }
}

// ---------------- final gather-average (bf16 input) ----------------
__global__ __launch_bounds__(256) void gather_kernel(const u16* __restrict__ xf,
                                                     void* __restrict__ out,
                                                     const int* __restrict__ flagp)
{
    int isbf = *flagp;
    int gid = blockIdx.x * 256 + threadIdx.x;    // pixel*128 + 4-elem chunk
    int p = gid >> 7, cv = gid & 127;
    int py = p >> 6, px = p & 63;
    float4 acc = make_float4(0.f, 0.f, 0.f, 0.f);
    int cnt = 0;
    #pragma unroll
    for (int dy = 0; dy < 2; dy++) {
        int y0 = ((py >> 3) - dy) << 3;
        if (y0 < 0) continue;
        #pragma unroll
        for (int dx = 0; dx < 2; dx++) {
            int x0 = ((px >> 3) - dx) << 3;
            if (x0 < 0) continue;
            int n = ((y0 >> 3) << 3) + (x0 >> 3);
            int s = (py - y0) * 16 + (px - x0);
            float4 t = bf4f(((const ushort4*)(xf + (size_t)(n * A_TOK + s) * C_DIM))[cv]);
            acc.x += t.x; acc.y += t.y; acc.z += t.z; acc.w += t.w;
            cnt++;
        }
    }
    float inv = 1.f / (float)cnt;
    acc.x *= inv; acc.y *= inv; acc.z *= inv; acc.w *= inv;
    if (isbf) {
        ushort4 o;
        o.x = f2bf(acc.x); o.y = f2bf(acc.y); o.z = f2bf(acc.z); o.w = f2bf(acc.w);
        ((ushort4*)out)[gid] = o;
    } else {
        ((float4*)out)[gid] = acc;
    }
}

extern "C" void kernel_launch(void* const* d_in, const int* in_sizes, int n_in,
                              void* d_out, int out_size, void* d_ws, size_t ws_size,
                              hipStream_t stream)
{
    const void* patch = d_in[0];
    const void* vox   = d_in[1];
    const void* ln1g  = d_in[2];
    const void* ln1b  = d_in[3];
    const void* wq = d_in[4];  const void* bq = d_in[5];
    const void* wk = d_in[6];  const void* bk = d_in[7];
    const void* wv = d_in[8];  const void* bv = d_in[9];
    const void* wo = d_in[10]; const void* bo = d_in[11];
    const void* ln2g = d_in[12];
    const void* ln2b = d_in[13];
    const void* w1 = d_in[14]; const void* b1 = d_in[15];
    const void* w2 = d_in[16]; const void* b2 = d_in[17];
    const int* vpy = (const int*)d_in[18];
    const int* vpx = (const int*)d_in[19];

    const size_t MB = 1ull << 20;
    char* ws = (char*)d_ws;
    if (ws_size < 183 * MB) return;   // insufficient workspace -> visible failure

    u16*  hbuf  = (u16*)(ws + 0);          // [32768][512] bf16, 32MB
    u16*  kbuf  = (u16*)(ws + 32 * MB);    // [32768][512] bf16, 32MB
    u16*  vtt   = (u16*)(ws + 64 * MB);    // V^T [512][32768] bf16, 32MB
    u16*  qbuf  = (u16*)(ws + 96 * MB);    // [16384][512] bf16, 16MB (compact patch)
    u16*  obuf  = (u16*)(ws + 112 * MB);   // 16MB
    float* xbuf = (float*)(ws + 128 * MB); // [16384][512] f32, 32MB
    u16*  h2buf = (u16*)(ws + 160 * MB);   // 16MB
    u16*  tbuf  = (u16*)(ws + 0);          // [16384][2048] bf16, 64MB (reuse h+k, dead)
    u16*  xfbuf = (u16*)(ws + 64 * MB);    // [16384][512] bf16, 16MB (reuse vtt, dead)
    u16* wqkvT = (u16*)(ws + 176 * MB);    // [1536][512] bf16, 1.5MB (q rows pre-scaled)
    u16* woT  = (u16*)(ws + 177 * MB + 512 * 1024);
    u16* w1T  = (u16*)(ws + 178 * MB);     // [2048][512], 2MB
    u16* w2T  = (u16*)(ws + 180 * MB);     // [512][2048], 2MB
    int* sel = (int*)(ws + 182 * MB);      // 64KB
    unsigned char* validk = (unsigned char*)(ws + 182 * MB + 64 * 1024); // 32KB
    int* flagp = (int*)(ws + 182 * MB + 128 * 1024);
    float* bqkv = (float*)(ws + 182 * MB + 132 * 1024);  // [1536] f32

    detect_kernel<<<1, 256, 0, stream>>>((const u32*)patch, flagp);

    dim3 blkT(32, 8);
    wtrans_kernel<<<dim3(16, 16), blkT, 0, stream>>>(wq, wqkvT,              512, 512,  flagp, 0.125f);
    wtrans_kernel<<<dim3(16, 16), blkT, 0, stream>>>(wk, wqkvT + 512 * 512,  512, 512,  flagp, 1.f);
    wtrans_kernel<<<dim3(16, 16), blkT, 0, stream>>>(wv, wqkvT + 1024 * 512, 512, 512,  flagp, 1.f);
    wtrans_kernel<<<dim3(16, 16), blkT, 0, stream>>>(wo, woT,                512, 512,  flagp, 1.f);
    wtrans_kernel<<<dim3(64, 16), blkT, 0, stream>>>(w1, w1T,                512, 2048, flagp, 1.f);
    wtrans_kernel<<<dim3(16, 64), blkT, 0, stream>>>(w2, w2T,                2048, 512, flagp, 1.f);
    prep_bias_kernel<<<6, 256, 0, stream>>>(bq, bk, bv, flagp, bqkv);

    voxsel_kernel<<<NWIN, 64, 0, stream>>>(vpy, vpx, sel);
    ln1_kernel<<<NROW / 4, 256, 0, stream>>>(patch, vox, ln1g, ln1b, sel, flagp, hbuf, validk);

    // fused QKV gemm: N=1536 (q compact/scaled | k | v^T via operand swap)
    gemm_kernel<<<dim3(12, NROW / 128), 256, 0, stream>>>(hbuf, wqkvT, bqkv,
        qbuf, kbuf, vtt, nullptr, flagp, NROW, 1536, 512, GF_QKV, 512);

    attn_kernel<<<dim3(HEADS, NWIN), 256, 0, stream>>>(qbuf, kbuf, vtt, validk, obuf);

    // x = tokens(patch gather) + o @ wo + bo   (f32)
    gemm_kernel<<<dim3(4, NPATCH / 128), 256, 0, stream>>>(obuf, woT, bo,
        xbuf, nullptr, nullptr, patch, flagp, NPATCH, 512, 512, GF_OUT_F32 | GF_RES_PATCH, 512);

    ln2_kernel<<<NPATCH / 4, 256, 0, stream>>>(xbuf, ln2g, ln2b, flagp, h2buf);

    gemm_kernel<<<dim3(16, NPATCH / 128), 256, 0, stream>>>(h2buf, w1T, b1,
        tbuf, nullptr, nullptr, nullptr, flagp, NPATCH, 2048, 512, GF_GELU, 2048);
    gemm_kernel<<<dim3(4, NPATCH / 128), 256, 0, stream>>>(tbuf, w2T, b2,
        xfbuf, nullptr, nullptr, xbuf, flagp, NPATCH, 512, 2048, GF_RES_F32, 512);

    gather_kernel<<<(4096 * 128) / 256, 256, 0, stream>>>(xfbuf, d_out, flagp);
}